// Round 5
// baseline (611.233 us; speedup 1.0000x reference)
//
#include <hip/hip_runtime.h>
#include <math.h>

#define B_ 16
#define N_ 512
#define D_ 32
#define E_ 8176
#define SLEFT_ 16384
#define FSS_ 601
#define BN_ (B_*N_)            // 8192
#define BE_ (B_*E_)            // 130816
#define NSROW_ (SLEFT_ + 2*E_) // 32736
#define OUT_R_ (B_*FSS_)       // 9616

typedef __attribute__((ext_vector_type(8))) short short8;
typedef __attribute__((ext_vector_type(4))) float f32x4;

typedef __attribute__((address_space(3))) uint lds_uint;
typedef __attribute__((address_space(1))) const uint g_uint;

__device__ __forceinline__ void gl_lds16(const ushort* gp, ushort* lp) {
  __builtin_amdgcn_global_load_lds((g_uint*)gp, (lds_uint*)lp, 16, 0, 0);
}

__device__ __forceinline__ ushort f2b(float f) {
  uint u = __builtin_bit_cast(uint, f);
  u += 0x7FFFu + ((u >> 16) & 1u);
  return (ushort)(u >> 16);
}
__device__ __forceinline__ float b2f(ushort h) {
  return __builtin_bit_cast(float, ((uint)h) << 16);
}

// ---------------- index / CSR build ----------------

__global__ __launch_bounds__(256) void k_indices(const float* __restrict__ ns,
                                                 int* __restrict__ src_i,
                                                 int* __restrict__ dst_i,
                                                 int* __restrict__ cnt) {
  int idx = blockIdx.x*256 + threadIdx.x;
  if (idx >= BE_) return;
  int b = idx / E_;
  int j = idx - b*E_;
  const float* row = ns + (size_t)b*NSROW_;
  int s = (int)row[SLEFT_ + j];
  int r = (int)row[SLEFT_ + E_ + j];
  src_i[idx] = b*N_ + s;
  int dst = b*N_ + r;
  dst_i[idx] = dst;
  atomicAdd(&cnt[dst], 1);
}

__global__ __launch_bounds__(1024) void k_scan(const int* __restrict__ cnt,
                                               int* __restrict__ rowptr) {
  __shared__ int part[1024];
  int t = threadIdx.x;
  int base = t*8;
  int loc[8]; int s = 0;
  #pragma unroll
  for (int i=0;i<8;i++){ loc[i]=cnt[base+i]; s+=loc[i]; }
  part[t]=s; __syncthreads();
  for (int off=1; off<1024; off<<=1) {
    int v = (t>=off)?part[t-off]:0;
    __syncthreads();
    part[t]+=v;
    __syncthreads();
  }
  int ex = (t==0)?0:part[t-1];
  #pragma unroll
  for (int i=0;i<8;i++){ rowptr[base+i]=ex; ex+=loc[i]; }
  if (t==1023) rowptr[BN_]=ex;
}

__global__ __launch_bounds__(256) void k_scatter(const int* __restrict__ src_i,
                                                 const int* __restrict__ dst_i,
                                                 const int* __restrict__ rowptr,
                                                 int* __restrict__ fill,
                                                 int* __restrict__ csr_src) {
  int idx = blockIdx.x*256+threadIdx.x;
  if (idx>=BE_) return;
  int dst = dst_i[idx];
  int pos = rowptr[dst] + atomicAdd(&fill[dst],1);
  csr_src[pos] = src_i[idx];
}

// ---------------- sa (bf16, padded to K=64) ----------------

__global__ __launch_bounds__(256) void k_sa(const float* __restrict__ ns,
                                            const int* __restrict__ a,
                                            ushort* __restrict__ sa) {
  int idx = blockIdx.x*256+threadIdx.x;
  if (idx >= BN_*64) return;
  int v = idx >> 6, c = idx & 63;
  int b = v >> 9, n = v & 511;
  float val = 0.f;
  if (c < 32)       val = ns[(size_t)b*NSROW_ + n*32 + c];
  else if (c == 32) val = (a[b]==n) ? 1.f : 0.f;
  sa[idx] = f2b(val);
}

// ---------------- all weight transposes in one kernel ----------------

struct WtP { const float* W[8]; ushort* T[8]; };

__global__ __launch_bounds__(256) void k_wt_all(WtP p) {
  int idx = blockIdx.x*256+threadIdx.x;
#define SEG(s, BASE, LIM, DIN, DOUT, KP, NP)                                 \
  if (idx < LIM) { int l = idx - BASE; int k = l / NP; int n = l - k*NP;     \
    float v = (k<DIN && n<DOUT) ? p.W[s][(size_t)k*DOUT+n] : 0.f;            \
    p.T[s][(size_t)n*KP + k] = f2b(v); return; }
  SEG(0, 0,       40960,   33, 601,  64, 640)
  SEG(1, 40960,   430080,  601,601, 608, 640)
  SEG(2, 430080,  819200,  601,601, 608, 640)
  SEG(3, 819200,  1208320, 601,601, 608, 640)
  SEG(4, 1208320, 1216512, 33, 128,  64, 128)
  SEG(5, 1216512, 1232896, 128, 64, 128, 128)
  SEG(6, 1232896, 1241088, 64,  64,  64, 128)
  SEG(7, 1241088, 1249280, 64,  32,  64, 128)
#undef SEG
}

// ---------------- MFMA bf16 GEMM with global_load_lds + fused es/ed ------
// 128x128 tile, BK=32, unpadded LDS (row stride 32 ushorts = 64B).
// Epilogue: per-64-col-tile partial dots with a_src/a_dst -> es_part/ed_part.

__global__ __launch_bounds__(256) void k_gemm(const ushort* __restrict__ A,
                                              const ushort* __restrict__ Bt,
                                              ushort* __restrict__ C,
                                              float* __restrict__ es_part,
                                              float* __restrict__ ed_part,
                                              const float* __restrict__ asrc,
                                              const float* __restrict__ adst,
                                              int Kpad, int ldc, int Nout, int dout) {
  __shared__ ushort Asm[128*32];
  __shared__ ushort Bsm[128*32];
  int tid = threadIdx.x;
  int rowBase = blockIdx.y * 128;
  int colBase = blockIdx.x * 128;
  int wave = tid >> 6, lane = tid & 63;
  int wr = (wave >> 1) * 64, wc = (wave & 1) * 64;
  int lm = lane & 15, lk = (lane >> 4) * 8;

  f32x4 acc[4][4];
  #pragma unroll
  for (int i=0;i<4;i++)
    #pragma unroll
    for (int j=0;j<4;j++) acc[i][j] = (f32x4){0.f,0.f,0.f,0.f};

  int t0 = tid, t1 = tid + 256;
  const ushort* Ag0 = A  + (size_t)(rowBase + (t0>>2))*Kpad + (t0&3)*8;
  const ushort* Ag1 = A  + (size_t)(rowBase + (t1>>2))*Kpad + (t1&3)*8;
  const ushort* Bg0 = Bt + (size_t)(colBase + (t0>>2))*Kpad + (t0&3)*8;
  const ushort* Bg1 = Bt + (size_t)(colBase + (t1>>2))*Kpad + (t1&3)*8;
  ushort* Al0 = &Asm[t0*8]; ushort* Al1 = &Asm[t1*8];
  ushort* Bl0 = &Bsm[t0*8]; ushort* Bl1 = &Bsm[t1*8];

  for (int k0 = 0; k0 < Kpad; k0 += 32) {
    gl_lds16(Ag0 + k0, Al0);
    gl_lds16(Ag1 + k0, Al1);
    gl_lds16(Bg0 + k0, Bl0);
    gl_lds16(Bg1 + k0, Bl1);
    __syncthreads();
    short8 af[4], bfr[4];
    #pragma unroll
    for (int i=0;i<4;i++) af[i]  = *(short8*)&Asm[(wr + i*16 + lm)*32 + lk];
    #pragma unroll
    for (int j=0;j<4;j++) bfr[j] = *(short8*)&Bsm[(wc + j*16 + lm)*32 + lk];
    #pragma unroll
    for (int i=0;i<4;i++)
      #pragma unroll
      for (int j=0;j<4;j++)
        acc[i][j] = __builtin_amdgcn_mfma_f32_16x16x32_bf16(af[i], bfr[j], acc[i][j], 0,0,0);
    __syncthreads();
  }

  // a_src / a_dst values for this wave's 4 column groups
  float asv[4], adv[4];
  #pragma unroll
  for (int j=0;j<4;j++) {
    int col = colBase + wc + j*16 + lm;
    asv[j] = (col < dout) ? asrc[col] : 0.f;
    adv[j] = (col < dout) ? adst[col] : 0.f;
  }
  int cr = lane >> 4;
  int ct2 = blockIdx.x*2 + (wc >> 6);   // 64-col es tile index
  #pragma unroll
  for (int i=0;i<4;i++) {
    // C write
    #pragma unroll
    for (int j=0;j<4;j++) {
      int col = colBase + wc + j*16 + lm;
      if (col < Nout) {
        #pragma unroll
        for (int g=0; g<4; g++) {
          int row = rowBase + wr + i*16 + cr*4 + g;
          C[(size_t)row*ldc + col] = f2b(acc[i][j][g]);
        }
      }
    }
    // es/ed partials
    #pragma unroll
    for (int g=0; g<4; g++) {
      float se = 0.f, sd = 0.f;
      #pragma unroll
      for (int j=0;j<4;j++) { se += acc[i][j][g]*asv[j]; sd += acc[i][j][g]*adv[j]; }
      #pragma unroll
      for (int o=1;o<16;o<<=1) { se += __shfl_xor(se,o,64); sd += __shfl_xor(sd,o,64); }
      if (lm == 0) {
        int row = rowBase + wr + i*16 + cr*4 + g;
        es_part[(size_t)ct2*BN_ + row] = se;
        ed_part[(size_t)ct2*BN_ + row] = sd;
      }
    }
  }
}

// ---------------- softmax + aggregation (one wave per node) ------
// es/ed reconstructed by summing nte 64-col-tile partials.
// Fast path (deg<=64): one lane per edge, weights kept in registers,
// serial gather gets (w,u) via __shfl; depth-2 prefetch.

__global__ __launch_bounds__(256) void k_agg(const ushort* __restrict__ h,
                                             const float* __restrict__ esp,
                                             const float* __restrict__ edp,
                                             const int* __restrict__ rowptr,
                                             const int* __restrict__ csr,
                                             const float* __restrict__ bias,
                                             ushort* __restrict__ g,
                                             int dout, int hld, int nte) {
  int wid = threadIdx.x>>6, lane = threadIdx.x&63;
  int bid = blockIdx.x;
  int xcd = bid & 7, slot = bid >> 3;
  int graph = xcd + ((slot >> 7) << 3);
  int v = graph*512 + (slot & 127)*4 + wid;
  int s0 = rowptr[v], e0 = rowptr[v+1];
  int deg = e0 - s0;

  float edv = 0.f;
  for (int t=0;t<nte;t++) edv += edp[(size_t)t*BN_ + v];

  int nch = (dout + 7) >> 3;
  int ch0 = lane, ch1 = lane + 64;
  bool a0 = ch0 < nch, a1 = ch1 < nch;
  float acc0[8], acc1[8];
  #pragma unroll
  for (int q=0;q<8;q++){ acc0[q]=0.f; acc1[q]=0.f; }

  if (deg <= 64) {
    bool has = lane < deg;
    int u = 0; float e = -__builtin_inff();
    if (has) {
      u = csr[s0 + lane];
      float s = 0.f;
      for (int t=0;t<nte;t++) s += esp[(size_t)t*BN_ + u];
      e = s + edv;
      e = e > 0.f ? e : 0.2f*e;
    }
    float m = e;
    #pragma unroll
    for (int o=32;o;o>>=1) m = fmaxf(m, __shfl_xor(m,o,64));
    float p = has ? __expf(e - m) : 0.f;
    float den = p;
    #pragma unroll
    for (int o=32;o;o>>=1) den += __shfl_xor(den,o,64);
    p *= 1.f/(den + 1e-16f);

    short8 A0{}, Bv0{}, A1{}, Bv1{};
    float w0 = 0.f, w1 = 0.f;
    if (deg > 0) {
      w0 = __shfl(p, 0, 64); int uu = __shfl(u, 0, 64);
      const ushort* hp = h + (size_t)uu*hld;
      if (a0) A0  = *(const short8*)&hp[ch0*8];
      if (a1) Bv0 = *(const short8*)&hp[ch1*8];
    }
    if (deg > 1) {
      w1 = __shfl(p, 1, 64); int uu = __shfl(u, 1, 64);
      const ushort* hp = h + (size_t)uu*hld;
      if (a0) A1  = *(const short8*)&hp[ch0*8];
      if (a1) Bv1 = *(const short8*)&hp[ch1*8];
    }
    for (int t = 0; t < deg; ++t) {
      short8 A2{}, Bv2{}; float w2 = 0.f;
      if (t+2 < deg) {
        w2 = __shfl(p, t+2, 64); int uu = __shfl(u, t+2, 64);
        const ushort* hp = h + (size_t)uu*hld;
        if (a0) A2  = *(const short8*)&hp[ch0*8];
        if (a1) Bv2 = *(const short8*)&hp[ch1*8];
      }
      if (a0) {
        #pragma unroll
        for (int q=0;q<8;q++) acc0[q] += w0 * b2f((ushort)A0[q]);
      }
      if (a1) {
        #pragma unroll
        for (int q=0;q<8;q++) acc1[q] += w0 * b2f((ushort)Bv0[q]);
      }
      A0=A1; Bv0=Bv1; w0=w1; A1=A2; Bv1=Bv2; w1=w2;
    }
  } else {
    // slow path (degree > 64) — should be rare/never for this input
    float m = -__builtin_inff();
    for (int j = s0 + lane; j < e0; j += 64) {
      int uu = csr[j]; float s = 0.f;
      for (int t=0;t<nte;t++) s += esp[(size_t)t*BN_ + uu];
      float e = s + edv; e = e > 0.f ? e : 0.2f*e;
      m = fmaxf(m, e);
    }
    #pragma unroll
    for (int o=32;o;o>>=1) m = fmaxf(m, __shfl_xor(m,o,64));
    float den = 0.f;
    for (int j = s0 + lane; j < e0; j += 64) {
      int uu = csr[j]; float s = 0.f;
      for (int t=0;t<nte;t++) s += esp[(size_t)t*BN_ + uu];
      float e = s + edv; e = e > 0.f ? e : 0.2f*e;
      den += __expf(e - m);
    }
    #pragma unroll
    for (int o=32;o;o>>=1) den += __shfl_xor(den,o,64);
    float scale = 1.f/(den + 1e-16f);
    for (int j = s0; j < e0; ++j) {
      int uu = csr[j]; float s = 0.f;
      for (int t=0;t<nte;t++) s += esp[(size_t)t*BN_ + uu];
      float e = s + edv; e = e > 0.f ? e : 0.2f*e;
      float wgt = __expf(e - m) * scale;
      const ushort* hp = h + (size_t)uu*hld;
      if (a0) {
        short8 hv = *(const short8*)&hp[ch0*8];
        #pragma unroll
        for (int q=0;q<8;q++) acc0[q] += wgt * b2f((ushort)hv[q]);
      }
      if (a1) {
        short8 hv = *(const short8*)&hp[ch1*8];
        #pragma unroll
        for (int q=0;q<8;q++) acc1[q] += wgt * b2f((ushort)hv[q]);
      }
    }
  }

  ushort* gv = g + (size_t)v*hld;
  if (a0) {
    short8 ov;
    #pragma unroll
    for (int q=0;q<8;q++) {
      int c = ch0*8+q;
      float val = (c < dout) ? acc0[q] + bias[c] : 0.f;
      ov[q] = (short)f2b(val);
    }
    *(short8*)&gv[ch0*8] = ov;
  }
  if (a1) {
    short8 ov;
    #pragma unroll
    for (int q=0;q<8;q++) {
      int c = ch1*8+q;
      float val = (c < dout) ? acc1[q] + bias[c] : 0.f;
      ov[q] = (short)f2b(val);
    }
    *(short8*)&gv[ch1*8] = ov;
  }
}

// ---------------- LN stats partials (no atomics) ----------------
// grid (cols/64, B, 8); writes st[z][{s,q}][b][c]

__global__ __launch_bounds__(256) void k_ln_stats3(const ushort* __restrict__ g,
                                                   float* __restrict__ st,
                                                   int ldg, int dout) {
  int b = blockIdx.y, z = blockIdx.z; int n0 = z*64;
  int lc = threadIdx.x & 63, r0 = threadIdx.x >> 6;
  int c = blockIdx.x*64 + lc;
  float s=0.f, q=0.f;
  if (c < dout) {
    #pragma unroll 4
    for (int i=0;i<16;i++) {
      int n = n0 + r0*16 + i;
      float x = b2f(g[(size_t)(b*N_+n)*ldg + c]);
      s+=x; q+=x*x;
    }
  }
  __shared__ float S[4][64], Q[4][64];
  S[r0][lc]=s; Q[r0][lc]=q; __syncthreads();
  if (r0==0 && c<dout) {
    st[((size_t)(z*2+0)*B_ + b)*dout + c] = S[0][lc]+S[1][lc]+S[2][lc]+S[3][lc];
    st[((size_t)(z*2+1)*B_ + b)*dout + c] = Q[0][lc]+Q[1][lc]+Q[2][lc]+Q[3][lc];
  }
}

// finalize: mu & rstd per (b, c)
__global__ __launch_bounds__(256) void k_stfin(const float* __restrict__ st,
                                               float* __restrict__ muf,
                                               float* __restrict__ rsf,
                                               int dout) {
  int c = blockIdx.x*256 + threadIdx.x;
  int b = blockIdx.y;
  if (c >= dout) return;
  float s=0.f, q=0.f;
  #pragma unroll
  for (int z=0;z<8;z++) {
    s += st[((size_t)(z*2+0)*B_ + b)*dout + c];
    q += st[((size_t)(z*2+1)*B_ + b)*dout + c];
  }
  float mu = s*(1.f/N_);
  float var = q*(1.f/N_) - mu*mu;
  muf[(size_t)b*dout + c] = mu;
  rsf[(size_t)b*dout + c] = rsqrtf(var + 1e-5f);
}

// ---------------- LN apply + ReLU -> padded bf16 input ----------------

__global__ __launch_bounds__(256) void k_ln_apply3(const ushort* __restrict__ g,
                                                   const float* __restrict__ muf,
                                                   const float* __restrict__ rsf,
                                                   const float* __restrict__ sc,
                                                   const float* __restrict__ of,
                                                   ushort* __restrict__ xb,
                                                   int ldg, int dout, int Kpad) {
  int tid = threadIdx.x;
  int p = blockIdx.x*128 + (tid & 127);
  int v = blockIdx.y*2 + (tid >> 7);
  int c0 = p*2;
  if (c0 >= Kpad) return;
  int b = v >> 9;
  uint gg = *(const uint*)&g[(size_t)v*ldg + c0];
  ushort r01[2] = {(ushort)(gg & 0xFFFFu), (ushort)(gg >> 16)};
  ushort ov[2];
  #pragma unroll
  for (int q=0;q<2;q++) {
    int c = c0+q;
    float y = 0.f;
    if (c < dout) {
      float x = b2f(r01[q]);
      y = (x - muf[(size_t)b*dout+c])*rsf[(size_t)b*dout+c]*sc[c] + of[c];
      y = y>0.f ? y : 0.f;
    }
    ov[q] = f2b(y);
  }
  *(uint*)&xb[(size_t)v*Kpad + c0] = ((uint)ov[1]<<16) | ov[0];
}

// ---------------- reward: sum over nodes (slot partials) ----------------

__global__ __launch_bounds__(256) void k_rsum(const ushort* __restrict__ g,
                                              float* __restrict__ rsp) {
  int b = blockIdx.y, z = blockIdx.z; int n0 = z*64;
  int lc = threadIdx.x & 63, r0 = threadIdx.x>>6;
  int c = blockIdx.x*64 + lc;
  float s = 0.f;
  if (c < FSS_) {
    #pragma unroll 4
    for (int i=0;i<16;i++) {
      int n = n0 + r0*16 + i;
      s += b2f(g[(size_t)(b*N_+n)*640 + c]);
    }
  }
  __shared__ float S[4][64];
  S[r0][lc]=s; __syncthreads();
  if (r0==0 && c<FSS_)
    rsp[((size_t)z*B_ + b)*FSS_ + c] = S[0][lc]+S[1][lc]+S[2][lc]+S[3][lc];
}

__global__ __launch_bounds__(256) void k_rfin(const float* __restrict__ rsp,
                                              float* __restrict__ out) {
  int c = blockIdx.x*256 + threadIdx.x;
  int b = blockIdx.y;
  if (c >= FSS_) return;
  float s = 0.f;
  #pragma unroll
  for (int z=0;z<8;z++) s += rsp[((size_t)z*B_ + b)*FSS_ + c];
  out[b*FSS_ + c] = s;
}

// ---------------- ns_new assembly ----------------

__global__ __launch_bounds__(256) void k_output(const ushort* __restrict__ f,
                                                const float* __restrict__ ns,
                                                float* __restrict__ out) {
  int idx = blockIdx.x*256+threadIdx.x;
  if (idx >= B_*NSROW_) return;
  int b = idx / NSROW_; int j = idx - b*NSROW_;
  float v = (j < SLEFT_) ? b2f(f[(size_t)b*SLEFT_ + j]) : ns[(size_t)b*NSROW_ + j];
  out[OUT_R_ + idx] = v;
}

// ---------------- host driver ----------------

static void gat_layer(const ushort* xb, int Kpad, int dout, int hld, int Npadt,
                      const ushort* Wt, const float* as, const float* ad, const float* bias,
                      const float* sc, const float* of, ushort* xb_next, int Kpad_next,
                      ushort* h, ushort* g, float* esp, float* edp,
                      float* stp, float* muf, float* rsf,
                      const int* rowptr, const int* csr_src, hipStream_t stream) {
  int nte = Npadt / 64;
  k_gemm<<<dim3(Npadt/128, BN_/128), 256, 0, stream>>>(xb, Wt, h, esp, edp, as, ad,
                                                       Kpad, hld, hld, dout);
  k_agg<<<BN_/4, 256, 0, stream>>>(h, esp, edp, rowptr, csr_src, bias, g, dout, hld, nte);
  if (sc) {
    k_ln_stats3<<<dim3((dout+63)/64, B_, 8), 256, 0, stream>>>(g, stp, hld, dout);
    k_stfin<<<dim3((dout+255)/256, B_), 256, 0, stream>>>(stp, muf, rsf, dout);
    k_ln_apply3<<<dim3((Kpad_next+255)/256, BN_/2), 256, 0, stream>>>(g, muf, rsf, sc, of,
                                                                      xb_next, hld, dout, Kpad_next);
  }
}

extern "C" void kernel_launch(void* const* d_in, const int* in_sizes, int n_in,
                              void* d_out, int out_size, void* d_ws, size_t ws_size,
                              hipStream_t stream) {
  const float* ns = (const float*)d_in[0];
  const int*   a  = (const int*)d_in[1];

  const float *W[4], *As[4], *Ad[4], *Bb[4], *Sc[3], *Of[3];
  const float *rW[4], *rAs[4], *rAd[4], *rBb[4], *rSc[3], *rOf[3];
  int p = 2;
  for (int i=0;i<4;i++){
    W[i]=(const float*)d_in[p++]; As[i]=(const float*)d_in[p++];
    Ad[i]=(const float*)d_in[p++]; Bb[i]=(const float*)d_in[p++];
    if (i<3){ Sc[i]=(const float*)d_in[p++]; Of[i]=(const float*)d_in[p++]; }
  }
  for (int i=0;i<4;i++){
    rW[i]=(const float*)d_in[p++]; rAs[i]=(const float*)d_in[p++];
    rAd[i]=(const float*)d_in[p++]; rBb[i]=(const float*)d_in[p++];
    if (i<3){ rSc[i]=(const float*)d_in[p++]; rOf[i]=(const float*)d_in[p++]; }
  }

  char* w = (char*)d_ws;
  auto carve = [&](size_t bytes)->void* {
    void* r = (void*)w;
    w += (bytes + 255) & ~(size_t)255;
    return r;
  };
  ushort* xb   = (ushort*)carve((size_t)BN_*608*2);
  ushort* hbuf = (ushort*)carve((size_t)BN_*640*2);
  ushort* gbuf = (ushort*)carve((size_t)BN_*640*2);
  ushort* sabf = (ushort*)carve((size_t)BN_*64*2);
  float* esp   = (float*)carve((size_t)10*BN_*4);
  float* edp   = (float*)carve((size_t)10*BN_*4);
  float* stp   = (float*)carve((size_t)16*B_*FSS_*4);
  float* muf   = (float*)carve((size_t)B_*FSS_*4);
  float* rsf   = (float*)carve((size_t)B_*FSS_*4);
  float* rsp   = (float*)carve((size_t)8*B_*FSS_*4);
  int* src_i   = (int*)carve((size_t)BE_*4);
  int* dst_i   = (int*)carve((size_t)BE_*4);
  int* cnt     = (int*)carve((size_t)BN_*4);
  int* rowptr  = (int*)carve((size_t)(BN_+1)*4);
  int* fill    = (int*)carve((size_t)BN_*4);
  int* csr_src = (int*)carve((size_t)BE_*4);
  ushort* rWt[4]; ushort* nWt[4];
  rWt[0] = (ushort*)carve((size_t)640*64*2);
  for (int i=1;i<4;i++) rWt[i] = (ushort*)carve((size_t)640*608*2);
  nWt[0] = (ushort*)carve((size_t)128*64*2);
  nWt[1] = (ushort*)carve((size_t)128*128*2);
  nWt[2] = (ushort*)carve((size_t)128*64*2);
  nWt[3] = (ushort*)carve((size_t)128*64*2);

  float* out = (float*)d_out;

  hipMemsetAsync(cnt,  0, (size_t)BN_*4, stream);
  hipMemsetAsync(fill, 0, (size_t)BN_*4, stream);

  k_indices<<<(BE_+255)/256, 256, 0, stream>>>(ns, src_i, dst_i, cnt);
  k_scan<<<1, 1024, 0, stream>>>(cnt, rowptr);
  k_scatter<<<(BE_+255)/256, 256, 0, stream>>>(src_i, dst_i, rowptr, fill, csr_src);
  k_sa<<<(BN_*64+255)/256, 256, 0, stream>>>(ns, a, sabf);

  WtP wtp;
  for (int i=0;i<4;i++){ wtp.W[i]=rW[i]; wtp.T[i]=rWt[i]; }
  for (int i=0;i<4;i++){ wtp.W[4+i]=W[i]; wtp.T[4+i]=nWt[i]; }
  k_wt_all<<<(1249280+255)/256, 256, 0, stream>>>(wtp);

  // reward head: (Kpad, dout, hld, Npadt, Kpad_next)
  gat_layer(sabf, 64,  FSS_, 640, 640, rWt[0], rAs[0],rAd[0],rBb[0], rSc[0],rOf[0], xb, 608,
            hbuf, gbuf, esp, edp, stp, muf, rsf, rowptr, csr_src, stream);
  gat_layer(xb,   608, FSS_, 640, 640, rWt[1], rAs[1],rAd[1],rBb[1], rSc[1],rOf[1], xb, 608,
            hbuf, gbuf, esp, edp, stp, muf, rsf, rowptr, csr_src, stream);
  gat_layer(xb,   608, FSS_, 640, 640, rWt[2], rAs[2],rAd[2],rBb[2], rSc[2],rOf[2], xb, 608,
            hbuf, gbuf, esp, edp, stp, muf, rsf, rowptr, csr_src, stream);
  gat_layer(xb,   608, FSS_, 640, 640, rWt[3], rAs[3],rAd[3],rBb[3], nullptr,nullptr, nullptr, 0,
            hbuf, gbuf, esp, edp, stp, muf, rsf, rowptr, csr_src, stream);
  k_rsum<<<dim3(10, B_, 8), 256, 0, stream>>>(gbuf, rsp);
  k_rfin<<<dim3((FSS_+255)/256, B_), 256, 0, stream>>>(rsp, out);

  // next-state head
  gat_layer(sabf, 64,  128, 128, 128, nWt[0], As[0],Ad[0],Bb[0], Sc[0],Of[0], xb, 128,
            hbuf, gbuf, esp, edp, stp, muf, rsf, rowptr, csr_src, stream);
  gat_layer(xb,   128, 64,  64,  128, nWt[1], As[1],Ad[1],Bb[1], Sc[1],Of[1], xb, 64,
            hbuf, gbuf, esp, edp, stp, muf, rsf, rowptr, csr_src, stream);
  gat_layer(xb,   64,  64,  64,  128, nWt[2], As[2],Ad[2],Bb[2], Sc[2],Of[2], xb, 64,
            hbuf, gbuf, esp, edp, stp, muf, rsf, rowptr, csr_src, stream);
  gat_layer(xb,   64,  32,  32,  128, nWt[3], As[3],Ad[3],Bb[3], nullptr,nullptr, nullptr, 0,
            hbuf, gbuf, esp, edp, stp, muf, rsf, rowptr, csr_src, stream);
  k_output<<<(B_*NSROW_+255)/256, 256, 0, stream>>>(gbuf, ns, out);
}

// Round 6
// 550.229 us; speedup vs baseline: 1.1109x; 1.1109x over previous
//
#include <hip/hip_runtime.h>
#include <math.h>

#define B_ 16
#define N_ 512
#define D_ 32
#define E_ 8176
#define SLEFT_ 16384
#define FSS_ 601
#define BN_ (B_*N_)            // 8192
#define BE_ (B_*E_)            // 130816
#define NSROW_ (SLEFT_ + 2*E_) // 32736
#define OUT_R_ (B_*FSS_)       // 9616
#define HLD_ 768               // combined h width: reward 0..639, next 640..767

typedef __attribute__((ext_vector_type(8))) short short8;
typedef __attribute__((ext_vector_type(4))) float f32x4;

typedef __attribute__((address_space(3))) uint lds_uint;
typedef __attribute__((address_space(1))) const uint g_uint;

__device__ __forceinline__ void gl_lds16(const ushort* gp, ushort* lp) {
  __builtin_amdgcn_global_load_lds((g_uint*)gp, (lds_uint*)lp, 16, 0, 0);
}

__device__ __forceinline__ ushort f2b(float f) {
  uint u = __builtin_bit_cast(uint, f);
  u += 0x7FFFu + ((u >> 16) & 1u);
  return (ushort)(u >> 16);
}
__device__ __forceinline__ float b2f(ushort h) {
  return __builtin_bit_cast(float, ((uint)h) << 16);
}

// ---------------- index / CSR build ----------------

__global__ __launch_bounds__(256) void k_indices(const float* __restrict__ ns,
                                                 int* __restrict__ src_i,
                                                 int* __restrict__ dst_i,
                                                 int* __restrict__ cnt) {
  int idx = blockIdx.x*256 + threadIdx.x;
  if (idx >= BE_) return;
  int b = idx / E_;
  int j = idx - b*E_;
  const float* row = ns + (size_t)b*NSROW_;
  int s = (int)row[SLEFT_ + j];
  int r = (int)row[SLEFT_ + E_ + j];
  src_i[idx] = b*N_ + s;
  int dst = b*N_ + r;
  dst_i[idx] = dst;
  atomicAdd(&cnt[dst], 1);
}

__global__ __launch_bounds__(1024) void k_scan(const int* __restrict__ cnt,
                                               int* __restrict__ rowptr) {
  __shared__ int part[1024];
  int t = threadIdx.x;
  int base = t*8;
  int loc[8]; int s = 0;
  #pragma unroll
  for (int i=0;i<8;i++){ loc[i]=cnt[base+i]; s+=loc[i]; }
  part[t]=s; __syncthreads();
  for (int off=1; off<1024; off<<=1) {
    int v = (t>=off)?part[t-off]:0;
    __syncthreads();
    part[t]+=v;
    __syncthreads();
  }
  int ex = (t==0)?0:part[t-1];
  #pragma unroll
  for (int i=0;i<8;i++){ rowptr[base+i]=ex; ex+=loc[i]; }
  if (t==1023) rowptr[BN_]=ex;
}

__global__ __launch_bounds__(256) void k_scatter(const int* __restrict__ src_i,
                                                 const int* __restrict__ dst_i,
                                                 const int* __restrict__ rowptr,
                                                 int* __restrict__ fill,
                                                 int* __restrict__ csr_src) {
  int idx = blockIdx.x*256+threadIdx.x;
  if (idx>=BE_) return;
  int dst = dst_i[idx];
  int pos = rowptr[dst] + atomicAdd(&fill[dst],1);
  csr_src[pos] = src_i[idx];
}

// ---------------- sa (bf16, padded to K=64) ----------------

__global__ __launch_bounds__(256) void k_sa(const float* __restrict__ ns,
                                            const int* __restrict__ a,
                                            ushort* __restrict__ sa) {
  int idx = blockIdx.x*256+threadIdx.x;
  if (idx >= BN_*64) return;
  int v = idx >> 6, c = idx & 63;
  int b = v >> 9, n = v & 511;
  float val = 0.f;
  if (c < 32)       val = ns[(size_t)b*NSROW_ + n*32 + c];
  else if (c == 32) val = (a[b]==n) ? 1.f : 0.f;
  sa[idx] = f2b(val);
}

// ---------------- block-diagonal combined weight transposes ----------------
// Wt [768][Kpad]: rows 0..639 = reward W^T (601 cols real, K at 0..dinR-1),
// rows 640..767 = next W^T (doutN real, K at koffN..koffN+dinN-1).

struct WtP { const float* Wr[4]; const float* Wn[4]; ushort* T[4]; };

__global__ __launch_bounds__(256) void k_wt_all(WtP p) {
  int idx = blockIdx.x*256+threadIdx.x;
#define SEG(s, BASE, LIM, KP, DINR, DINN, DOUTN, KOFF)                         \
  if (idx < LIM) { int l = idx - BASE; int n = l % 768; int k = l / 768;       \
    float v = 0.f;                                                             \
    if (n < 640) { if (n < 601 && k < DINR) v = p.Wr[s][(size_t)k*601 + n]; }  \
    else { int nn = n - 640; int kk = k - KOFF;                                \
           if (nn < DOUTN && kk >= 0 && kk < DINN)                             \
             v = p.Wn[s][(size_t)kk*DOUTN + nn]; }                             \
    p.T[s][(size_t)n*KP + k] = f2b(v); return; }
  SEG(0, 0,       49152,   64,  33,  33,  128, 0)
  SEG(1, 49152,   614400,  736, 601, 128, 64,  608)
  SEG(2, 614400,  1130496, 672, 601, 64,  64,  608)
  SEG(3, 1130496, 1646592, 672, 601, 64,  32,  608)
#undef SEG
}

// ---------------- MFMA bf16 GEMM (combined heads) + fused es/ed -----------
// 128x128 tile, BK=32, global_load_lds staging. C is [BN][768].
// Epilogue: per-64-col-tile partial dots -> esed[row*24 + tile*2 + {0,1}].

__global__ __launch_bounds__(256) void k_gemm(const ushort* __restrict__ A,
                                              const ushort* __restrict__ Bt,
                                              ushort* __restrict__ C,
                                              float* __restrict__ esed,
                                              const float* __restrict__ asr,
                                              const float* __restrict__ adr,
                                              const float* __restrict__ asn,
                                              const float* __restrict__ adn,
                                              int Kpad, int dn) {
  __shared__ ushort Asm[128*32];
  __shared__ ushort Bsm[128*32];
  int tid = threadIdx.x;
  int rowBase = blockIdx.y * 128;
  int colBase = blockIdx.x * 128;
  int wave = tid >> 6, lane = tid & 63;
  int wr = (wave >> 1) * 64, wc = (wave & 1) * 64;
  int lm = lane & 15, lk = (lane >> 4) * 8;

  f32x4 acc[4][4];
  #pragma unroll
  for (int i=0;i<4;i++)
    #pragma unroll
    for (int j=0;j<4;j++) acc[i][j] = (f32x4){0.f,0.f,0.f,0.f};

  int t0 = tid, t1 = tid + 256;
  const ushort* Ag0 = A  + (size_t)(rowBase + (t0>>2))*Kpad + (t0&3)*8;
  const ushort* Ag1 = A  + (size_t)(rowBase + (t1>>2))*Kpad + (t1&3)*8;
  const ushort* Bg0 = Bt + (size_t)(colBase + (t0>>2))*Kpad + (t0&3)*8;
  const ushort* Bg1 = Bt + (size_t)(colBase + (t1>>2))*Kpad + (t1&3)*8;
  ushort* Al0 = &Asm[t0*8]; ushort* Al1 = &Asm[t1*8];
  ushort* Bl0 = &Bsm[t0*8]; ushort* Bl1 = &Bsm[t1*8];

  for (int k0 = 0; k0 < Kpad; k0 += 32) {
    gl_lds16(Ag0 + k0, Al0);
    gl_lds16(Ag1 + k0, Al1);
    gl_lds16(Bg0 + k0, Bl0);
    gl_lds16(Bg1 + k0, Bl1);
    __syncthreads();
    short8 af[4], bfr[4];
    #pragma unroll
    for (int i=0;i<4;i++) af[i]  = *(short8*)&Asm[(wr + i*16 + lm)*32 + lk];
    #pragma unroll
    for (int j=0;j<4;j++) bfr[j] = *(short8*)&Bsm[(wc + j*16 + lm)*32 + lk];
    #pragma unroll
    for (int i=0;i<4;i++)
      #pragma unroll
      for (int j=0;j<4;j++)
        acc[i][j] = __builtin_amdgcn_mfma_f32_16x16x32_bf16(af[i], bfr[j], acc[i][j], 0,0,0);
    __syncthreads();
  }

  // attention a-vector values for this wave's 4 column groups
  float asv[4], adv[4];
  #pragma unroll
  for (int j=0;j<4;j++) {
    int col = colBase + wc + j*16 + lm;
    float s = 0.f, d = 0.f;
    if (col < 601)      { s = asr[col];     d = adr[col]; }
    else if (col >= 640 && col - 640 < dn) { s = asn[col-640]; d = adn[col-640]; }
    asv[j] = s; adv[j] = d;
  }
  int cr = lane >> 4;
  int ct2 = blockIdx.x*2 + (wc >> 6);   // 64-col tile index (0..11)
  #pragma unroll
  for (int i=0;i<4;i++) {
    #pragma unroll
    for (int j=0;j<4;j++) {
      int col = colBase + wc + j*16 + lm;
      #pragma unroll
      for (int g=0; g<4; g++) {
        int row = rowBase + wr + i*16 + cr*4 + g;
        C[(size_t)row*HLD_ + col] = f2b(acc[i][j][g]);
      }
    }
    #pragma unroll
    for (int g=0; g<4; g++) {
      float se = 0.f, sd = 0.f;
      #pragma unroll
      for (int j=0;j<4;j++) { se += acc[i][j][g]*asv[j]; sd += acc[i][j][g]*adv[j]; }
      #pragma unroll
      for (int o=1;o<16;o<<=1) { se += __shfl_xor(se,o,64); sd += __shfl_xor(sd,o,64); }
      if (lm == 0) {
        int row = rowBase + wr + i*16 + cr*4 + g;
        esed[(size_t)row*24 + ct2*2 + 0] = se;
        esed[(size_t)row*24 + ct2*2 + 1] = sd;
      }
    }
  }
}

// ---------------- combined softmax + aggregation (one wave per node) ------
// es_r = sum tiles 0..9, es_n = tiles 10..11. Both heads gathered from one
// shared edge stream (one csr load, one h-row address).

__global__ __launch_bounds__(256) void k_agg(const ushort* __restrict__ h,
                                             const float* __restrict__ esed,
                                             const int* __restrict__ rowptr,
                                             const int* __restrict__ csr,
                                             const float* __restrict__ bias_r,
                                             const float* __restrict__ bias_n,
                                             ushort* __restrict__ g,
                                             int dn) {
  int wid = threadIdx.x>>6, lane = threadIdx.x&63;
  int bid = blockIdx.x;
  int xcd = bid & 7, slot = bid >> 3;
  int graph = xcd + ((slot >> 7) << 3);
  int v = graph*512 + (slot & 127)*4 + wid;
  int s0 = rowptr[v], e0 = rowptr[v+1];
  int deg = e0 - s0;

  // dest terms
  float edr = 0.f, edn = 0.f;
  {
    const float* ep = esed + (size_t)v*24;
    #pragma unroll
    for (int t=0;t<10;t++) edr += ep[2*t+1];
    edn = ep[21] + ep[23];
  }

  int ch0 = lane, ch1 = lane + 64;          // 96 chunks of 8 cols
  bool a1 = ch1 < 96;
  float acc0[8], acc1[8];
  #pragma unroll
  for (int q=0;q<8;q++){ acc0[q]=0.f; acc1[q]=0.f; }

  if (deg <= 64) {
    bool has = lane < deg;
    int u = 0; float er = -__builtin_inff(), en = -__builtin_inff();
    if (has) {
      u = csr[s0 + lane];
      const float* ep = esed + (size_t)u*24;
      float sr = 0.f;
      #pragma unroll
      for (int t=0;t<10;t++) sr += ep[2*t];
      float sn = ep[20] + ep[22];
      er = sr + edr; er = er > 0.f ? er : 0.2f*er;
      en = sn + edn; en = en > 0.f ? en : 0.2f*en;
    }
    float mr = er, mn = en;
    #pragma unroll
    for (int o=32;o;o>>=1) { mr = fmaxf(mr, __shfl_xor(mr,o,64)); mn = fmaxf(mn, __shfl_xor(mn,o,64)); }
    float pr = has ? __expf(er - mr) : 0.f;
    float pn = has ? __expf(en - mn) : 0.f;
    float dr = pr, dnm = pn;
    #pragma unroll
    for (int o=32;o;o>>=1) { dr += __shfl_xor(dr,o,64); dnm += __shfl_xor(dnm,o,64); }
    pr *= 1.f/(dr + 1e-16f);
    pn *= 1.f/(dnm + 1e-16f);

    short8 A0{}, Bv0{}, A1{}, Bv1{};
    float w0r=0.f, w0n=0.f, w1r=0.f, w1n=0.f;
    if (deg > 0) {
      w0r = __shfl(pr, 0, 64); w0n = __shfl(pn, 0, 64); int uu = __shfl(u, 0, 64);
      const ushort* hp = h + (size_t)uu*HLD_;
      A0 = *(const short8*)&hp[ch0*8];
      if (a1) Bv0 = *(const short8*)&hp[ch1*8];
    }
    if (deg > 1) {
      w1r = __shfl(pr, 1, 64); w1n = __shfl(pn, 1, 64); int uu = __shfl(u, 1, 64);
      const ushort* hp = h + (size_t)uu*HLD_;
      A1 = *(const short8*)&hp[ch0*8];
      if (a1) Bv1 = *(const short8*)&hp[ch1*8];
    }
    bool c1r = ch1 < 80;   // ch1 76..79 is zero-pad h, weight irrelevant
    for (int t = 0; t < deg; ++t) {
      short8 A2{}, Bv2{}; float w2r=0.f, w2n=0.f;
      if (t+2 < deg) {
        w2r = __shfl(pr, t+2, 64); w2n = __shfl(pn, t+2, 64); int uu = __shfl(u, t+2, 64);
        const ushort* hp = h + (size_t)uu*HLD_;
        A2 = *(const short8*)&hp[ch0*8];
        if (a1) Bv2 = *(const short8*)&hp[ch1*8];
      }
      #pragma unroll
      for (int q=0;q<8;q++) acc0[q] += w0r * b2f((ushort)A0[q]);
      if (a1) {
        float w = c1r ? w0r : w0n;
        #pragma unroll
        for (int q=0;q<8;q++) acc1[q] += w * b2f((ushort)Bv0[q]);
      }
      A0=A1; Bv0=Bv1; w0r=w1r; w0n=w1n;
      A1=A2; Bv1=Bv2; w1r=w2r; w1n=w2n;
    }
  } else {
    // slow path (degree > 64)
    float mr = -__builtin_inff(), mn = -__builtin_inff();
    for (int j = s0 + lane; j < e0; j += 64) {
      const float* ep = esed + (size_t)csr[j]*24;
      float sr=0.f; for (int t=0;t<10;t++) sr += ep[2*t];
      float sn = ep[20]+ep[22];
      float er = sr + edr; er = er>0.f?er:0.2f*er;
      float en = sn + edn; en = en>0.f?en:0.2f*en;
      mr = fmaxf(mr, er); mn = fmaxf(mn, en);
    }
    #pragma unroll
    for (int o=32;o;o>>=1) { mr=fmaxf(mr,__shfl_xor(mr,o,64)); mn=fmaxf(mn,__shfl_xor(mn,o,64)); }
    float dr=0.f, dnm=0.f;
    for (int j = s0 + lane; j < e0; j += 64) {
      const float* ep = esed + (size_t)csr[j]*24;
      float sr=0.f; for (int t=0;t<10;t++) sr += ep[2*t];
      float sn = ep[20]+ep[22];
      float er = sr + edr; er = er>0.f?er:0.2f*er;
      float en = sn + edn; en = en>0.f?en:0.2f*en;
      dr += __expf(er-mr); dnm += __expf(en-mn);
    }
    #pragma unroll
    for (int o=32;o;o>>=1) { dr+=__shfl_xor(dr,o,64); dnm+=__shfl_xor(dnm,o,64); }
    float ir = 1.f/(dr+1e-16f), in_ = 1.f/(dnm+1e-16f);
    bool c1r = ch1 < 80;
    for (int j = s0; j < e0; ++j) {
      int uu = csr[j];
      const float* ep = esed + (size_t)uu*24;
      float sr=0.f; for (int t=0;t<10;t++) sr += ep[2*t];
      float sn = ep[20]+ep[22];
      float er = sr + edr; er = er>0.f?er:0.2f*er;
      float en = sn + edn; en = en>0.f?en:0.2f*en;
      float wr2 = __expf(er-mr)*ir, wn2 = __expf(en-mn)*in_;
      const ushort* hp = h + (size_t)uu*HLD_;
      short8 hv = *(const short8*)&hp[ch0*8];
      #pragma unroll
      for (int q=0;q<8;q++) acc0[q] += wr2 * b2f((ushort)hv[q]);
      if (a1) {
        short8 hv2 = *(const short8*)&hp[ch1*8];
        float w = c1r ? wr2 : wn2;
        #pragma unroll
        for (int q=0;q<8;q++) acc1[q] += w * b2f((ushort)hv2[q]);
      }
    }
  }

  ushort* gv = g + (size_t)v*HLD_;
  {
    int cb = ch0*8;              // <= 504, all reward-real
    short8 ov;
    #pragma unroll
    for (int q=0;q<8;q++) ov[q] = (short)f2b(acc0[q] + bias_r[cb+q]);
    *(short8*)&gv[cb] = ov;
  }
  if (a1) {
    int cb = ch1*8;              // 512..759
    short8 ov;
    #pragma unroll
    for (int q=0;q<8;q++) {
      int c = cb+q;
      float val;
      if (c < 601)                         val = acc1[q] + bias_r[c];
      else if (c >= 640 && (c-640) < dn)   val = acc1[q] + bias_n[c-640];
      else                                 val = 0.f;
      ov[q] = (short)f2b(val);
    }
    *(short8*)&gv[cb] = ov;
  }
}

// ---------------- LN stats partials over all 768 cols ----------------
// grid (12, B, 8); writes st[(z*2+{0,1})*B + b][768]

__global__ __launch_bounds__(256) void k_ln_stats(const ushort* __restrict__ g,
                                                  float* __restrict__ st) {
  int b = blockIdx.y, z = blockIdx.z; int n0 = z*64;
  int lc = threadIdx.x & 63, r0 = threadIdx.x >> 6;
  int c = blockIdx.x*64 + lc;
  float s=0.f, q=0.f;
  #pragma unroll 4
  for (int i=0;i<16;i++) {
    int n = n0 + r0*16 + i;
    float x = b2f(g[(size_t)(b*N_+n)*HLD_ + c]);
    s+=x; q+=x*x;
  }
  __shared__ float S[4][64], Q[4][64];
  S[r0][lc]=s; Q[r0][lc]=q; __syncthreads();
  if (r0==0) {
    st[((size_t)(z*2+0)*B_ + b)*HLD_ + c] = S[0][lc]+S[1][lc]+S[2][lc]+S[3][lc];
    st[((size_t)(z*2+1)*B_ + b)*HLD_ + c] = Q[0][lc]+Q[1][lc]+Q[2][lc]+Q[3][lc];
  }
}

// ---------------- LN apply + ReLU -> combined padded bf16 input -----------
// xb[v][c]: c<608 -> reward (src g col c, params r), c>=608 -> next
// (src g col 640+(c-608), params n). Finalize (8-partial sum) folded in.

__global__ __launch_bounds__(256) void k_ln_apply(const ushort* __restrict__ g,
                                                  const float* __restrict__ st,
                                                  const float* __restrict__ scr,
                                                  const float* __restrict__ ofr,
                                                  const float* __restrict__ scn,
                                                  const float* __restrict__ ofn,
                                                  ushort* __restrict__ xb,
                                                  int dn, int Kpad) {
  int tid = threadIdx.x;
  int p = blockIdx.x*128 + (tid & 127);
  int v = blockIdx.y*2 + (tid >> 7);
  int c0 = p*2;
  if (c0 >= Kpad) return;
  int b = v >> 9;
  ushort ov[2];
  #pragma unroll
  for (int q=0;q<2;q++) {
    int c = c0+q;
    int cs; bool valid; float scale, offs;
    if (c < 608) { cs = c; valid = c < 601;
                   scale = valid ? scr[c] : 0.f; offs = valid ? ofr[c] : 0.f; }
    else { int cn = c - 608; cs = 640 + cn; valid = cn < dn;
           scale = valid ? scn[cn] : 0.f; offs = valid ? ofn[cn] : 0.f; }
    float y = 0.f;
    if (valid) {
      float s=0.f, qq=0.f;
      #pragma unroll
      for (int z=0;z<8;z++) {
        s  += st[((size_t)(z*2+0)*B_ + b)*HLD_ + cs];
        qq += st[((size_t)(z*2+1)*B_ + b)*HLD_ + cs];
      }
      float mu = s*(1.f/N_);
      float var = qq*(1.f/N_) - mu*mu;
      float x = b2f(g[(size_t)v*HLD_ + cs]);
      y = (x - mu)*rsqrtf(var+1e-5f)*scale + offs;
      y = y>0.f ? y : 0.f;
    }
    ov[q] = f2b(y);
  }
  *(uint*)&xb[(size_t)v*Kpad + c0] = ((uint)ov[1]<<16) | ov[0];
}

// ---------------- reward: sum over nodes (slot partials) ----------------

__global__ __launch_bounds__(256) void k_rsum(const ushort* __restrict__ g,
                                              float* __restrict__ rsp) {
  int b = blockIdx.y, z = blockIdx.z; int n0 = z*64;
  int lc = threadIdx.x & 63, r0 = threadIdx.x>>6;
  int c = blockIdx.x*64 + lc;
  float s = 0.f;
  if (c < FSS_) {
    #pragma unroll 4
    for (int i=0;i<16;i++) {
      int n = n0 + r0*16 + i;
      s += b2f(g[(size_t)(b*N_+n)*HLD_ + c]);
    }
  }
  __shared__ float S[4][64];
  S[r0][lc]=s; __syncthreads();
  if (r0==0 && c<FSS_)
    rsp[((size_t)z*B_ + b)*FSS_ + c] = S[0][lc]+S[1][lc]+S[2][lc]+S[3][lc];
}

__global__ __launch_bounds__(256) void k_rfin(const float* __restrict__ rsp,
                                              float* __restrict__ out) {
  int c = blockIdx.x*256 + threadIdx.x;
  int b = blockIdx.y;
  if (c >= FSS_) return;
  float s = 0.f;
  #pragma unroll
  for (int z=0;z<8;z++) s += rsp[((size_t)z*B_ + b)*FSS_ + c];
  out[b*FSS_ + c] = s;
}

// ---------------- ns_new assembly (f = combined g cols 640..671) ----------

__global__ __launch_bounds__(256) void k_output(const ushort* __restrict__ g,
                                                const float* __restrict__ ns,
                                                float* __restrict__ out) {
  int idx = blockIdx.x*256+threadIdx.x;
  if (idx >= B_*NSROW_) return;
  int b = idx / NSROW_; int j = idx - b*NSROW_;
  float v;
  if (j < SLEFT_) {
    int n = j >> 5, c = j & 31;
    v = b2f(g[(size_t)(b*N_+n)*HLD_ + 640 + c]);
  } else {
    v = ns[(size_t)b*NSROW_ + j];
  }
  out[OUT_R_ + idx] = v;
}

// ---------------- host driver ----------------

extern "C" void kernel_launch(void* const* d_in, const int* in_sizes, int n_in,
                              void* d_out, int out_size, void* d_ws, size_t ws_size,
                              hipStream_t stream) {
  const float* ns = (const float*)d_in[0];
  const int*   a  = (const int*)d_in[1];

  const float *W[4], *As[4], *Ad[4], *Bb[4], *Sc[3], *Of[3];
  const float *rW[4], *rAs[4], *rAd[4], *rBb[4], *rSc[3], *rOf[3];
  int p = 2;
  for (int i=0;i<4;i++){
    W[i]=(const float*)d_in[p++]; As[i]=(const float*)d_in[p++];
    Ad[i]=(const float*)d_in[p++]; Bb[i]=(const float*)d_in[p++];
    if (i<3){ Sc[i]=(const float*)d_in[p++]; Of[i]=(const float*)d_in[p++]; }
  }
  for (int i=0;i<4;i++){
    rW[i]=(const float*)d_in[p++]; rAs[i]=(const float*)d_in[p++];
    rAd[i]=(const float*)d_in[p++]; rBb[i]=(const float*)d_in[p++];
    if (i<3){ rSc[i]=(const float*)d_in[p++]; rOf[i]=(const float*)d_in[p++]; }
  }

  char* w = (char*)d_ws;
  auto carve = [&](size_t bytes)->void* {
    void* r = (void*)w;
    w += (bytes + 255) & ~(size_t)255;
    return r;
  };
  ushort* xb   = (ushort*)carve((size_t)BN_*736*2);
  ushort* hbuf = (ushort*)carve((size_t)BN_*HLD_*2);
  ushort* gbuf = (ushort*)carve((size_t)BN_*HLD_*2);
  ushort* sabf = (ushort*)carve((size_t)BN_*64*2);
  float* esed  = (float*)carve((size_t)BN_*24*4);
  float* stp   = (float*)carve((size_t)16*B_*HLD_*4);
  float* rsp   = (float*)carve((size_t)8*B_*FSS_*4);
  int* src_i   = (int*)carve((size_t)BE_*4);
  int* dst_i   = (int*)carve((size_t)BE_*4);
  int* cnt     = (int*)carve((size_t)BN_*4);
  int* rowptr  = (int*)carve((size_t)(BN_+1)*4);
  int* fill    = (int*)carve((size_t)BN_*4);
  int* csr_src = (int*)carve((size_t)BE_*4);
  ushort* Wt[4];
  Wt[0] = (ushort*)carve((size_t)768*64*2);
  Wt[1] = (ushort*)carve((size_t)768*736*2);
  Wt[2] = (ushort*)carve((size_t)768*672*2);
  Wt[3] = (ushort*)carve((size_t)768*672*2);

  float* out = (float*)d_out;

  hipMemsetAsync(cnt,  0, (size_t)BN_*4, stream);
  hipMemsetAsync(fill, 0, (size_t)BN_*4, stream);

  k_indices<<<(BE_+255)/256, 256, 0, stream>>>(ns, src_i, dst_i, cnt);
  k_scan<<<1, 1024, 0, stream>>>(cnt, rowptr);
  k_scatter<<<(BE_+255)/256, 256, 0, stream>>>(src_i, dst_i, rowptr, fill, csr_src);
  k_sa<<<(BN_*64+255)/256, 256, 0, stream>>>(ns, a, sabf);

  WtP wtp;
  for (int i=0;i<4;i++){ wtp.Wr[i]=rW[i]; wtp.Wn[i]=W[i]; wtp.T[i]=Wt[i]; }
  k_wt_all<<<(1646592+255)/256, 256, 0, stream>>>(wtp);

  dim3 ggrid(6, BN_/128);

  // L1: K=64 (shared sa), dn=128
  k_gemm<<<ggrid, 256, 0, stream>>>(sabf, Wt[0], hbuf, esed, rAs[0],rAd[0],As[0],Ad[0], 64, 128);
  k_agg<<<BN_/4, 256, 0, stream>>>(hbuf, esed, rowptr, csr_src, rBb[0], Bb[0], gbuf, 128);
  k_ln_stats<<<dim3(12, B_, 8), 256, 0, stream>>>(gbuf, stp);
  k_ln_apply<<<dim3(3, BN_/2), 256, 0, stream>>>(gbuf, stp, rSc[0],rOf[0],Sc[0],Of[0], xb, 128, 736);

  // L2: K=736, dn=64
  k_gemm<<<ggrid, 256, 0, stream>>>(xb, Wt[1], hbuf, esed, rAs[1],rAd[1],As[1],Ad[1], 736, 64);
  k_agg<<<BN_/4, 256, 0, stream>>>(hbuf, esed, rowptr, csr_src, rBb[1], Bb[1], gbuf, 64);
  k_ln_stats<<<dim3(12, B_, 8), 256, 0, stream>>>(gbuf, stp);
  k_ln_apply<<<dim3(3, BN_/2), 256, 0, stream>>>(gbuf, stp, rSc[1],rOf[1],Sc[1],Of[1], xb, 64, 672);

  // L3: K=672, dn=64
  k_gemm<<<ggrid, 256, 0, stream>>>(xb, Wt[2], hbuf, esed, rAs[2],rAd[2],As[2],Ad[2], 672, 64);
  k_agg<<<BN_/4, 256, 0, stream>>>(hbuf, esed, rowptr, csr_src, rBb[2], Bb[2], gbuf, 64);
  k_ln_stats<<<dim3(12, B_, 8), 256, 0, stream>>>(gbuf, stp);
  k_ln_apply<<<dim3(3, BN_/2), 256, 0, stream>>>(gbuf, stp, rSc[2],rOf[2],Sc[2],Of[2], xb, 64, 672);

  // L4: K=672, dn=32, no LN
  k_gemm<<<ggrid, 256, 0, stream>>>(xb, Wt[3], hbuf, esed, rAs[3],rAd[3],As[3],Ad[3], 672, 32);
  k_agg<<<BN_/4, 256, 0, stream>>>(hbuf, esed, rowptr, csr_src, rBb[3], Bb[3], gbuf, 32);

  k_rsum<<<dim3(10, B_, 8), 256, 0, stream>>>(gbuf, rsp);
  k_rfin<<<dim3((FSS_+255)/256, B_), 256, 0, stream>>>(rsp, out);
  k_output<<<(B_*NSROW_+255)/256, 256, 0, stream>>>(gbuf, ns, out);
}

// Round 7
// 423.547 us; speedup vs baseline: 1.4431x; 1.2991x over previous
//
#include <hip/hip_runtime.h>
#include <math.h>

#define B_ 16
#define N_ 512
#define D_ 32
#define E_ 8176
#define SLEFT_ 16384
#define FSS_ 601
#define BN_ (B_*N_)            // 8192
#define BE_ (B_*E_)            // 130816
#define NSROW_ (SLEFT_ + 2*E_) // 32736
#define OUT_R_ (B_*FSS_)       // 9616
#define HLD_ 768               // combined h width: reward 0..639, next 640..767

typedef __attribute__((ext_vector_type(8))) short short8;
typedef __attribute__((ext_vector_type(4))) float f32x4;

typedef __attribute__((address_space(3))) uint lds_uint;
typedef __attribute__((address_space(1))) const uint g_uint;

__device__ __forceinline__ void gl_lds16(const ushort* gp, ushort* lp) {
  __builtin_amdgcn_global_load_lds((g_uint*)gp, (lds_uint*)lp, 16, 0, 0);
}

__device__ __forceinline__ ushort f2b(float f) {
  uint u = __builtin_bit_cast(uint, f);
  u += 0x7FFFu + ((u >> 16) & 1u);
  return (ushort)(u >> 16);
}
__device__ __forceinline__ float b2f(ushort h) {
  return __builtin_bit_cast(float, ((uint)h) << 16);
}

// ---------------- index / CSR build ----------------

__global__ __launch_bounds__(256) void k_indices(const float* __restrict__ ns,
                                                 int* __restrict__ src_i,
                                                 int* __restrict__ dst_i,
                                                 int* __restrict__ cnt) {
  int idx = blockIdx.x*256 + threadIdx.x;
  if (idx >= BE_) return;
  int b = idx / E_;
  int j = idx - b*E_;
  const float* row = ns + (size_t)b*NSROW_;
  int s = (int)row[SLEFT_ + j];
  int r = (int)row[SLEFT_ + E_ + j];
  src_i[idx] = b*N_ + s;
  int dst = b*N_ + r;
  dst_i[idx] = dst;
  atomicAdd(&cnt[dst], 1);
}

__global__ __launch_bounds__(1024) void k_scan(const int* __restrict__ cnt,
                                               int* __restrict__ rowptr) {
  __shared__ int part[1024];
  int t = threadIdx.x;
  int base = t*8;
  int loc[8]; int s = 0;
  #pragma unroll
  for (int i=0;i<8;i++){ loc[i]=cnt[base+i]; s+=loc[i]; }
  part[t]=s; __syncthreads();
  for (int off=1; off<1024; off<<=1) {
    int v = (t>=off)?part[t-off]:0;
    __syncthreads();
    part[t]+=v;
    __syncthreads();
  }
  int ex = (t==0)?0:part[t-1];
  #pragma unroll
  for (int i=0;i<8;i++){ rowptr[base+i]=ex; ex+=loc[i]; }
  if (t==1023) rowptr[BN_]=ex;
}

__global__ __launch_bounds__(256) void k_scatter(const int* __restrict__ src_i,
                                                 const int* __restrict__ dst_i,
                                                 const int* __restrict__ rowptr,
                                                 int* __restrict__ fill,
                                                 int* __restrict__ csr_src) {
  int idx = blockIdx.x*256+threadIdx.x;
  if (idx>=BE_) return;
  int dst = dst_i[idx];
  int pos = rowptr[dst] + atomicAdd(&fill[dst],1);
  csr_src[pos] = src_i[idx];
}

// ---------------- sa (bf16, padded to K=64) ----------------

__global__ __launch_bounds__(256) void k_sa(const float* __restrict__ ns,
                                            const int* __restrict__ a,
                                            ushort* __restrict__ sa) {
  int idx = blockIdx.x*256+threadIdx.x;
  if (idx >= BN_*64) return;
  int v = idx >> 6, c = idx & 63;
  int b = v >> 9, n = v & 511;
  float val = 0.f;
  if (c < 32)       val = ns[(size_t)b*NSROW_ + n*32 + c];
  else if (c == 32) val = (a[b]==n) ? 1.f : 0.f;
  sa[idx] = f2b(val);
}

// ---------------- block-diagonal combined weight transposes ----------------

struct WtP { const float* Wr[4]; const float* Wn[4]; ushort* T[4]; };

__global__ __launch_bounds__(256) void k_wt_all(WtP p) {
  int idx = blockIdx.x*256+threadIdx.x;
#define SEG(s, BASE, LIM, KP, DINR, DINN, DOUTN, KOFF)                         \
  if (idx < LIM) { int l = idx - BASE; int n = l % 768; int k = l / 768;       \
    float v = 0.f;                                                             \
    if (n < 640) { if (n < 601 && k < DINR) v = p.Wr[s][(size_t)k*601 + n]; }  \
    else { int nn = n - 640; int kk = k - KOFF;                                \
           if (nn < DOUTN && kk >= 0 && kk < DINN)                             \
             v = p.Wn[s][(size_t)kk*DOUTN + nn]; }                             \
    p.T[s][(size_t)n*KP + k] = f2b(v); return; }
  SEG(0, 0,       49152,   64,  33,  33,  128, 0)
  SEG(1, 49152,   614400,  736, 601, 128, 64,  608)
  SEG(2, 614400,  1130496, 672, 601, 64,  64,  608)
  SEG(3, 1130496, 1646592, 672, 601, 64,  32,  608)
#undef SEG
}

// ---------------- MFMA bf16 GEMM (combined heads) + fused es/ed -----------

__global__ __launch_bounds__(256) void k_gemm(const ushort* __restrict__ A,
                                              const ushort* __restrict__ Bt,
                                              ushort* __restrict__ C,
                                              float* __restrict__ esed,
                                              const float* __restrict__ asr,
                                              const float* __restrict__ adr,
                                              const float* __restrict__ asn,
                                              const float* __restrict__ adn,
                                              int Kpad, int dn) {
  __shared__ ushort Asm[128*32];
  __shared__ ushort Bsm[128*32];
  int tid = threadIdx.x;
  int rowBase = blockIdx.y * 128;
  int colBase = blockIdx.x * 128;
  int wave = tid >> 6, lane = tid & 63;
  int wr = (wave >> 1) * 64, wc = (wave & 1) * 64;
  int lm = lane & 15, lk = (lane >> 4) * 8;

  f32x4 acc[4][4];
  #pragma unroll
  for (int i=0;i<4;i++)
    #pragma unroll
    for (int j=0;j<4;j++) acc[i][j] = (f32x4){0.f,0.f,0.f,0.f};

  int t0 = tid, t1 = tid + 256;
  const ushort* Ag0 = A  + (size_t)(rowBase + (t0>>2))*Kpad + (t0&3)*8;
  const ushort* Ag1 = A  + (size_t)(rowBase + (t1>>2))*Kpad + (t1&3)*8;
  const ushort* Bg0 = Bt + (size_t)(colBase + (t0>>2))*Kpad + (t0&3)*8;
  const ushort* Bg1 = Bt + (size_t)(colBase + (t1>>2))*Kpad + (t1&3)*8;
  ushort* Al0 = &Asm[t0*8]; ushort* Al1 = &Asm[t1*8];
  ushort* Bl0 = &Bsm[t0*8]; ushort* Bl1 = &Bsm[t1*8];

  for (int k0 = 0; k0 < Kpad; k0 += 32) {
    gl_lds16(Ag0 + k0, Al0);
    gl_lds16(Ag1 + k0, Al1);
    gl_lds16(Bg0 + k0, Bl0);
    gl_lds16(Bg1 + k0, Bl1);
    __syncthreads();
    short8 af[4], bfr[4];
    #pragma unroll
    for (int i=0;i<4;i++) af[i]  = *(short8*)&Asm[(wr + i*16 + lm)*32 + lk];
    #pragma unroll
    for (int j=0;j<4;j++) bfr[j] = *(short8*)&Bsm[(wc + j*16 + lm)*32 + lk];
    #pragma unroll
    for (int i=0;i<4;i++)
      #pragma unroll
      for (int j=0;j<4;j++)
        acc[i][j] = __builtin_amdgcn_mfma_f32_16x16x32_bf16(af[i], bfr[j], acc[i][j], 0,0,0);
    __syncthreads();
  }

  float asv[4], adv[4];
  #pragma unroll
  for (int j=0;j<4;j++) {
    int col = colBase + wc + j*16 + lm;
    float s = 0.f, d = 0.f;
    if (col < 601)      { s = asr[col];     d = adr[col]; }
    else if (col >= 640 && col - 640 < dn) { s = asn[col-640]; d = adn[col-640]; }
    asv[j] = s; adv[j] = d;
  }
  int cr = lane >> 4;
  int ct2 = blockIdx.x*2 + (wc >> 6);
  #pragma unroll
  for (int i=0;i<4;i++) {
    #pragma unroll
    for (int j=0;j<4;j++) {
      int col = colBase + wc + j*16 + lm;
      #pragma unroll
      for (int g=0; g<4; g++) {
        int row = rowBase + wr + i*16 + cr*4 + g;
        C[(size_t)row*HLD_ + col] = f2b(acc[i][j][g]);
      }
    }
    #pragma unroll
    for (int g=0; g<4; g++) {
      float se = 0.f, sd = 0.f;
      #pragma unroll
      for (int j=0;j<4;j++) { se += acc[i][j][g]*asv[j]; sd += acc[i][j][g]*adv[j]; }
      #pragma unroll
      for (int o=1;o<16;o<<=1) { se += __shfl_xor(se,o,64); sd += __shfl_xor(sd,o,64); }
      if (lm == 0) {
        int row = rowBase + wr + i*16 + cr*4 + g;
        esed[(size_t)row*24 + ct2*2 + 0] = se;
        esed[(size_t)row*24 + ct2*2 + 1] = sd;
      }
    }
  }
}

// ---------------- combined softmax + aggregation (one wave per node) ------

__global__ __launch_bounds__(256) void k_agg(const ushort* __restrict__ h,
                                             const float* __restrict__ esed,
                                             const int* __restrict__ rowptr,
                                             const int* __restrict__ csr,
                                             const float* __restrict__ bias_r,
                                             const float* __restrict__ bias_n,
                                             ushort* __restrict__ g,
                                             int dn) {
  int wid = threadIdx.x>>6, lane = threadIdx.x&63;
  int bid = blockIdx.x;
  int xcd = bid & 7, slot = bid >> 3;
  int graph = xcd + ((slot >> 7) << 3);
  int v = graph*512 + (slot & 127)*4 + wid;
  int s0 = rowptr[v], e0 = rowptr[v+1];
  int deg = e0 - s0;

  float edr = 0.f, edn = 0.f;
  {
    const float* ep = esed + (size_t)v*24;
    #pragma unroll
    for (int t=0;t<10;t++) edr += ep[2*t+1];
    edn = ep[21] + ep[23];
  }

  int ch0 = lane, ch1 = lane + 64;
  bool a1 = ch1 < 96;
  float acc0[8], acc1[8];
  #pragma unroll
  for (int q=0;q<8;q++){ acc0[q]=0.f; acc1[q]=0.f; }

  if (deg <= 64) {
    bool has = lane < deg;
    int u = 0; float er = -__builtin_inff(), en = -__builtin_inff();
    if (has) {
      u = csr[s0 + lane];
      const float* ep = esed + (size_t)u*24;
      float sr = 0.f;
      #pragma unroll
      for (int t=0;t<10;t++) sr += ep[2*t];
      float sn = ep[20] + ep[22];
      er = sr + edr; er = er > 0.f ? er : 0.2f*er;
      en = sn + edn; en = en > 0.f ? en : 0.2f*en;
    }
    float mr = er, mn = en;
    #pragma unroll
    for (int o=32;o;o>>=1) { mr = fmaxf(mr, __shfl_xor(mr,o,64)); mn = fmaxf(mn, __shfl_xor(mn,o,64)); }
    float pr = has ? __expf(er - mr) : 0.f;
    float pn = has ? __expf(en - mn) : 0.f;
    float dr = pr, dnm = pn;
    #pragma unroll
    for (int o=32;o;o>>=1) { dr += __shfl_xor(dr,o,64); dnm += __shfl_xor(dnm,o,64); }
    pr *= 1.f/(dr + 1e-16f);
    pn *= 1.f/(dnm + 1e-16f);

    short8 A0{}, Bv0{}, A1{}, Bv1{};
    float w0r=0.f, w0n=0.f, w1r=0.f, w1n=0.f;
    if (deg > 0) {
      w0r = __shfl(pr, 0, 64); w0n = __shfl(pn, 0, 64); int uu = __shfl(u, 0, 64);
      const ushort* hp = h + (size_t)uu*HLD_;
      A0 = *(const short8*)&hp[ch0*8];
      if (a1) Bv0 = *(const short8*)&hp[ch1*8];
    }
    if (deg > 1) {
      w1r = __shfl(pr, 1, 64); w1n = __shfl(pn, 1, 64); int uu = __shfl(u, 1, 64);
      const ushort* hp = h + (size_t)uu*HLD_;
      A1 = *(const short8*)&hp[ch0*8];
      if (a1) Bv1 = *(const short8*)&hp[ch1*8];
    }
    bool c1r = ch1 < 80;
    for (int t = 0; t < deg; ++t) {
      short8 A2{}, Bv2{}; float w2r=0.f, w2n=0.f;
      if (t+2 < deg) {
        w2r = __shfl(pr, t+2, 64); w2n = __shfl(pn, t+2, 64); int uu = __shfl(u, t+2, 64);
        const ushort* hp = h + (size_t)uu*HLD_;
        A2 = *(const short8*)&hp[ch0*8];
        if (a1) Bv2 = *(const short8*)&hp[ch1*8];
      }
      #pragma unroll
      for (int q=0;q<8;q++) acc0[q] += w0r * b2f((ushort)A0[q]);
      if (a1) {
        float w = c1r ? w0r : w0n;
        #pragma unroll
        for (int q=0;q<8;q++) acc1[q] += w * b2f((ushort)Bv0[q]);
      }
      A0=A1; Bv0=Bv1; w0r=w1r; w0n=w1n;
      A1=A2; Bv1=Bv2; w1r=w2r; w1n=w2n;
    }
  } else {
    float mr = -__builtin_inff(), mn = -__builtin_inff();
    for (int j = s0 + lane; j < e0; j += 64) {
      const float* ep = esed + (size_t)csr[j]*24;
      float sr=0.f; for (int t=0;t<10;t++) sr += ep[2*t];
      float sn = ep[20]+ep[22];
      float er = sr + edr; er = er>0.f?er:0.2f*er;
      float en = sn + edn; en = en>0.f?en:0.2f*en;
      mr = fmaxf(mr, er); mn = fmaxf(mn, en);
    }
    #pragma unroll
    for (int o=32;o;o>>=1) { mr=fmaxf(mr,__shfl_xor(mr,o,64)); mn=fmaxf(mn,__shfl_xor(mn,o,64)); }
    float dr=0.f, dnm=0.f;
    for (int j = s0 + lane; j < e0; j += 64) {
      const float* ep = esed + (size_t)csr[j]*24;
      float sr=0.f; for (int t=0;t<10;t++) sr += ep[2*t];
      float sn = ep[20]+ep[22];
      float er = sr + edr; er = er>0.f?er:0.2f*er;
      float en = sn + edn; en = en>0.f?en:0.2f*en;
      dr += __expf(er-mr); dnm += __expf(en-mn);
    }
    #pragma unroll
    for (int o=32;o;o>>=1) { dr+=__shfl_xor(dr,o,64); dnm+=__shfl_xor(dnm,o,64); }
    float ir = 1.f/(dr+1e-16f), in_ = 1.f/(dnm+1e-16f);
    bool c1r = ch1 < 80;
    for (int j = s0; j < e0; ++j) {
      int uu = csr[j];
      const float* ep = esed + (size_t)uu*24;
      float sr=0.f; for (int t=0;t<10;t++) sr += ep[2*t];
      float sn = ep[20]+ep[22];
      float er = sr + edr; er = er>0.f?er:0.2f*er;
      float en = sn + edn; en = en>0.f?en:0.2f*en;
      float wr2 = __expf(er-mr)*ir, wn2 = __expf(en-mn)*in_;
      const ushort* hp = h + (size_t)uu*HLD_;
      short8 hv = *(const short8*)&hp[ch0*8];
      #pragma unroll
      for (int q=0;q<8;q++) acc0[q] += wr2 * b2f((ushort)hv[q]);
      if (a1) {
        short8 hv2 = *(const short8*)&hp[ch1*8];
        float w = c1r ? wr2 : wn2;
        #pragma unroll
        for (int q=0;q<8;q++) acc1[q] += w * b2f((ushort)hv2[q]);
      }
    }
  }

  ushort* gv = g + (size_t)v*HLD_;
  {
    int cb = ch0*8;
    short8 ov;
    #pragma unroll
    for (int q=0;q<8;q++) ov[q] = (short)f2b(acc0[q] + bias_r[cb+q]);
    *(short8*)&gv[cb] = ov;
  }
  if (a1) {
    int cb = ch1*8;
    short8 ov;
    #pragma unroll
    for (int q=0;q<8;q++) {
      int c = cb+q;
      float val;
      if (c < 601)                         val = acc1[q] + bias_r[c];
      else if (c >= 640 && (c-640) < dn)   val = acc1[q] + bias_n[c-640];
      else                                 val = 0.f;
      ov[q] = (short)f2b(val);
    }
    *(short8*)&gv[cb] = ov;
  }
}

// ---------------- LN stats partials over all 768 cols ----------------

__global__ __launch_bounds__(256) void k_ln_stats(const ushort* __restrict__ g,
                                                  float* __restrict__ st) {
  int b = blockIdx.y, z = blockIdx.z; int n0 = z*64;
  int lc = threadIdx.x & 63, r0 = threadIdx.x >> 6;
  int c = blockIdx.x*64 + lc;
  float s=0.f, q=0.f;
  #pragma unroll 4
  for (int i=0;i<16;i++) {
    int n = n0 + r0*16 + i;
    float x = b2f(g[(size_t)(b*N_+n)*HLD_ + c]);
    s+=x; q+=x*x;
  }
  __shared__ float S[4][64], Q[4][64];
  S[r0][lc]=s; Q[r0][lc]=q; __syncthreads();
  if (r0==0) {
    st[((size_t)(z*2+0)*B_ + b)*HLD_ + c] = S[0][lc]+S[1][lc]+S[2][lc]+S[3][lc];
    st[((size_t)(z*2+1)*B_ + b)*HLD_ + c] = Q[0][lc]+Q[1][lc]+Q[2][lc]+Q[3][lc];
  }
}

// ---------------- LN finalize: mul/add per (b, xb col) ----------------
// mul = rstd*scale, add = offset - mu*rstd*scale; invalid cols -> 0.

__global__ __launch_bounds__(256) void k_stfin(const float* __restrict__ st,
                                               const float* __restrict__ scr,
                                               const float* __restrict__ ofr,
                                               const float* __restrict__ scn,
                                               const float* __restrict__ ofn,
                                               float* __restrict__ mulb,
                                               float* __restrict__ addb,
                                               int dn, int Kpad) {
  int c = blockIdx.x*256 + threadIdx.x;
  int b = blockIdx.y;
  if (c >= Kpad) return;
  int cs; bool valid; float scale, offs;
  if (c < 608) { cs = c; valid = c < 601;
                 scale = valid ? scr[c] : 0.f; offs = valid ? ofr[c] : 0.f; }
  else { int cn = c - 608; cs = 640 + cn; valid = cn < dn;
         scale = valid ? scn[cn] : 0.f; offs = valid ? ofn[cn] : 0.f; }
  float mul = 0.f, add = 0.f;
  if (valid) {
    float s=0.f, qq=0.f;
    #pragma unroll
    for (int z=0;z<8;z++) {
      s  += st[((size_t)(z*2+0)*B_ + b)*HLD_ + cs];
      qq += st[((size_t)(z*2+1)*B_ + b)*HLD_ + cs];
    }
    float mu = s*(1.f/N_);
    float var = qq*(1.f/N_) - mu*mu;
    float rs = rsqrtf(var+1e-5f);
    mul = rs*scale;
    add = offs - mu*rs*scale;
  }
  mulb[(size_t)b*Kpad + c] = mul;
  addb[(size_t)b*Kpad + c] = add;
}

// ---------------- LN apply + ReLU (thread owns col pair, loops 16 rows) ---

__global__ __launch_bounds__(256) void k_ln_apply(const ushort* __restrict__ g,
                                                  const float* __restrict__ mulb,
                                                  const float* __restrict__ addb,
                                                  ushort* __restrict__ xb,
                                                  int Kpad) {
  int tid = threadIdx.x;
  int pp = blockIdx.x*128 + (tid & 127);
  int c0 = pp*2;
  if (c0 >= Kpad) return;
  int vbase = blockIdx.y*16;
  int b = vbase >> 9;
  int cs0 = (c0 < 608) ? c0 : 640 + (c0 - 608);
  float m0 = mulb[(size_t)b*Kpad + c0],     a0 = addb[(size_t)b*Kpad + c0];
  float m1 = mulb[(size_t)b*Kpad + c0 + 1], a1 = addb[(size_t)b*Kpad + c0 + 1];
  for (int i = tid >> 7; i < 16; i += 2) {
    int v = vbase + i;
    uint gg = *(const uint*)&g[(size_t)v*HLD_ + cs0];
    float x0 = b2f((ushort)(gg & 0xFFFFu));
    float x1 = b2f((ushort)(gg >> 16));
    float y0 = x0*m0 + a0; y0 = y0 > 0.f ? y0 : 0.f;
    float y1 = x1*m1 + a1; y1 = y1 > 0.f ? y1 : 0.f;
    *(uint*)&xb[(size_t)v*Kpad + c0] = ((uint)f2b(y1) << 16) | f2b(y0);
  }
}

// ---------------- reward: sum over nodes (slot partials) ----------------

__global__ __launch_bounds__(256) void k_rsum(const ushort* __restrict__ g,
                                              float* __restrict__ rsp) {
  int b = blockIdx.y, z = blockIdx.z; int n0 = z*64;
  int lc = threadIdx.x & 63, r0 = threadIdx.x>>6;
  int c = blockIdx.x*64 + lc;
  float s = 0.f;
  if (c < FSS_) {
    #pragma unroll 4
    for (int i=0;i<16;i++) {
      int n = n0 + r0*16 + i;
      s += b2f(g[(size_t)(b*N_+n)*HLD_ + c]);
    }
  }
  __shared__ float S[4][64];
  S[r0][lc]=s; __syncthreads();
  if (r0==0 && c<FSS_)
    rsp[((size_t)z*B_ + b)*FSS_ + c] = S[0][lc]+S[1][lc]+S[2][lc]+S[3][lc];
}

__global__ __launch_bounds__(256) void k_rfin(const float* __restrict__ rsp,
                                              float* __restrict__ out) {
  int c = blockIdx.x*256 + threadIdx.x;
  int b = blockIdx.y;
  if (c >= FSS_) return;
  float s = 0.f;
  #pragma unroll
  for (int z=0;z<8;z++) s += rsp[((size_t)z*B_ + b)*FSS_ + c];
  out[b*FSS_ + c] = s;
}

// ---------------- ns_new assembly ----------------

__global__ __launch_bounds__(256) void k_output(const ushort* __restrict__ g,
                                                const float* __restrict__ ns,
                                                float* __restrict__ out) {
  int idx = blockIdx.x*256+threadIdx.x;
  if (idx >= B_*NSROW_) return;
  int b = idx / NSROW_; int j = idx - b*NSROW_;
  float v;
  if (j < SLEFT_) {
    int n = j >> 5, c = j & 31;
    v = b2f(g[(size_t)(b*N_+n)*HLD_ + 640 + c]);
  } else {
    v = ns[(size_t)b*NSROW_ + j];
  }
  out[OUT_R_ + idx] = v;
}

// ---------------- host driver ----------------

extern "C" void kernel_launch(void* const* d_in, const int* in_sizes, int n_in,
                              void* d_out, int out_size, void* d_ws, size_t ws_size,
                              hipStream_t stream) {
  const float* ns = (const float*)d_in[0];
  const int*   a  = (const int*)d_in[1];

  const float *W[4], *As[4], *Ad[4], *Bb[4], *Sc[3], *Of[3];
  const float *rW[4], *rAs[4], *rAd[4], *rBb[4], *rSc[3], *rOf[3];
  int p = 2;
  for (int i=0;i<4;i++){
    W[i]=(const float*)d_in[p++]; As[i]=(const float*)d_in[p++];
    Ad[i]=(const float*)d_in[p++]; Bb[i]=(const float*)d_in[p++];
    if (i<3){ Sc[i]=(const float*)d_in[p++]; Of[i]=(const float*)d_in[p++]; }
  }
  for (int i=0;i<4;i++){
    rW[i]=(const float*)d_in[p++]; rAs[i]=(const float*)d_in[p++];
    rAd[i]=(const float*)d_in[p++]; rBb[i]=(const float*)d_in[p++];
    if (i<3){ rSc[i]=(const float*)d_in[p++]; rOf[i]=(const float*)d_in[p++]; }
  }

  char* w = (char*)d_ws;
  auto carve = [&](size_t bytes)->void* {
    void* r = (void*)w;
    w += (bytes + 255) & ~(size_t)255;
    return r;
  };
  ushort* xb   = (ushort*)carve((size_t)BN_*736*2);
  ushort* hbuf = (ushort*)carve((size_t)BN_*HLD_*2);
  ushort* gbuf = (ushort*)carve((size_t)BN_*HLD_*2);
  ushort* sabf = (ushort*)carve((size_t)BN_*64*2);
  float* esed  = (float*)carve((size_t)BN_*24*4);
  float* stp   = (float*)carve((size_t)16*B_*HLD_*4);
  float* mulb  = (float*)carve((size_t)B_*736*4);
  float* addb  = (float*)carve((size_t)B_*736*4);
  float* rsp   = (float*)carve((size_t)8*B_*FSS_*4);
  int* src_i   = (int*)carve((size_t)BE_*4);
  int* dst_i   = (int*)carve((size_t)BE_*4);
  int* cnt     = (int*)carve((size_t)BN_*4);
  int* rowptr  = (int*)carve((size_t)(BN_+1)*4);
  int* fill    = (int*)carve((size_t)BN_*4);
  int* csr_src = (int*)carve((size_t)BE_*4);
  ushort* Wt[4];
  Wt[0] = (ushort*)carve((size_t)768*64*2);
  Wt[1] = (ushort*)carve((size_t)768*736*2);
  Wt[2] = (ushort*)carve((size_t)768*672*2);
  Wt[3] = (ushort*)carve((size_t)768*672*2);

  float* out = (float*)d_out;

  hipMemsetAsync(cnt,  0, (size_t)BN_*4, stream);
  hipMemsetAsync(fill, 0, (size_t)BN_*4, stream);

  k_indices<<<(BE_+255)/256, 256, 0, stream>>>(ns, src_i, dst_i, cnt);
  k_scan<<<1, 1024, 0, stream>>>(cnt, rowptr);
  k_scatter<<<(BE_+255)/256, 256, 0, stream>>>(src_i, dst_i, rowptr, fill, csr_src);
  k_sa<<<(BN_*64+255)/256, 256, 0, stream>>>(ns, a, sabf);

  WtP wtp;
  for (int i=0;i<4;i++){ wtp.Wr[i]=rW[i]; wtp.Wn[i]=W[i]; wtp.T[i]=Wt[i]; }
  k_wt_all<<<(1646592+255)/256, 256, 0, stream>>>(wtp);

  dim3 ggrid(6, BN_/128);

  // L1: K=64 (shared sa), dn=128
  k_gemm<<<ggrid, 256, 0, stream>>>(sabf, Wt[0], hbuf, esed, rAs[0],rAd[0],As[0],Ad[0], 64, 128);
  k_agg<<<BN_/4, 256, 0, stream>>>(hbuf, esed, rowptr, csr_src, rBb[0], Bb[0], gbuf, 128);
  k_ln_stats<<<dim3(12, B_, 8), 256, 0, stream>>>(gbuf, stp);
  k_stfin<<<dim3(3, B_), 256, 0, stream>>>(stp, rSc[0],rOf[0],Sc[0],Of[0], mulb, addb, 128, 736);
  k_ln_apply<<<dim3(3, BN_/16), 256, 0, stream>>>(gbuf, mulb, addb, xb, 736);

  // L2: K=736, dn=64
  k_gemm<<<ggrid, 256, 0, stream>>>(xb, Wt[1], hbuf, esed, rAs[1],rAd[1],As[1],Ad[1], 736, 64);
  k_agg<<<BN_/4, 256, 0, stream>>>(hbuf, esed, rowptr, csr_src, rBb[1], Bb[1], gbuf, 64);
  k_ln_stats<<<dim3(12, B_, 8), 256, 0, stream>>>(gbuf, stp);
  k_stfin<<<dim3(3, B_), 256, 0, stream>>>(stp, rSc[1],rOf[1],Sc[1],Of[1], mulb, addb, 64, 672);
  k_ln_apply<<<dim3(3, BN_/16), 256, 0, stream>>>(gbuf, mulb, addb, xb, 672);

  // L3: K=672, dn=64
  k_gemm<<<ggrid, 256, 0, stream>>>(xb, Wt[2], hbuf, esed, rAs[2],rAd[2],As[2],Ad[2], 672, 64);
  k_agg<<<BN_/4, 256, 0, stream>>>(hbuf, esed, rowptr, csr_src, rBb[2], Bb[2], gbuf, 64);
  k_ln_stats<<<dim3(12, B_, 8), 256, 0, stream>>>(gbuf, stp);
  k_stfin<<<dim3(3, B_), 256, 0, stream>>>(stp, rSc[2],rOf[2],Sc[2],Of[2], mulb, addb, 64, 672);
  k_ln_apply<<<dim3(3, BN_/16), 256, 0, stream>>>(gbuf, mulb, addb, xb, 672);

  // L4: K=672, dn=32, no LN
  k_gemm<<<ggrid, 256, 0, stream>>>(xb, Wt[3], hbuf, esed, rAs[3],rAd[3],As[3],Ad[3], 672, 32);
  k_agg<<<BN_/4, 256, 0, stream>>>(hbuf, esed, rowptr, csr_src, rBb[3], Bb[3], gbuf, 32);

  k_rsum<<<dim3(10, B_, 8), 256, 0, stream>>>(gbuf, rsp);
  k_rfin<<<dim3((FSS_+255)/256, B_), 256, 0, stream>>>(rsp, out);
  k_output<<<(B_*NSROW_+255)/256, 256, 0, stream>>>(gbuf, ns, out);
}

// Round 8
// 416.872 us; speedup vs baseline: 1.4662x; 1.0160x over previous
//
#include <hip/hip_runtime.h>
#include <math.h>

#define B_ 16
#define N_ 512
#define D_ 32
#define E_ 8176
#define SLEFT_ 16384
#define FSS_ 601
#define BN_ (B_*N_)            // 8192
#define BE_ (B_*E_)            // 130816
#define NSROW_ (SLEFT_ + 2*E_) // 32736
#define OUT_R_ (B_*FSS_)       // 9616
#define HLD_ 768               // combined h width: reward 0..639, next 640..767

typedef __attribute__((ext_vector_type(8))) short short8;
typedef __attribute__((ext_vector_type(4))) float f32x4;

typedef __attribute__((address_space(3))) uint lds_uint;
typedef __attribute__((address_space(1))) const uint g_uint;

__device__ __forceinline__ void gl_lds16(const ushort* gp, ushort* lp) {
  __builtin_amdgcn_global_load_lds((g_uint*)gp, (lds_uint*)lp, 16, 0, 0);
}

__device__ __forceinline__ ushort f2b(float f) {
  uint u = __builtin_bit_cast(uint, f);
  u += 0x7FFFu + ((u >> 16) & 1u);
  return (ushort)(u >> 16);
}
__device__ __forceinline__ float b2f(ushort h) {
  return __builtin_bit_cast(float, ((uint)h) << 16);
}

// ---------------- index / CSR build ----------------

__global__ __launch_bounds__(256) void k_indices(const float* __restrict__ ns,
                                                 int* __restrict__ src_i,
                                                 int* __restrict__ dst_i,
                                                 int* __restrict__ cnt) {
  int idx = blockIdx.x*256 + threadIdx.x;
  if (idx >= BE_) return;
  int b = idx / E_;
  int j = idx - b*E_;
  const float* row = ns + (size_t)b*NSROW_;
  int s = (int)row[SLEFT_ + j];
  int r = (int)row[SLEFT_ + E_ + j];
  src_i[idx] = b*N_ + s;
  int dst = b*N_ + r;
  dst_i[idx] = dst;
  atomicAdd(&cnt[dst], 1);
}

__global__ __launch_bounds__(1024) void k_scan(const int* __restrict__ cnt,
                                               int* __restrict__ rowptr) {
  __shared__ int part[1024];
  int t = threadIdx.x;
  int base = t*8;
  int loc[8]; int s = 0;
  #pragma unroll
  for (int i=0;i<8;i++){ loc[i]=cnt[base+i]; s+=loc[i]; }
  part[t]=s; __syncthreads();
  for (int off=1; off<1024; off<<=1) {
    int v = (t>=off)?part[t-off]:0;
    __syncthreads();
    part[t]+=v;
    __syncthreads();
  }
  int ex = (t==0)?0:part[t-1];
  #pragma unroll
  for (int i=0;i<8;i++){ rowptr[base+i]=ex; ex+=loc[i]; }
  if (t==1023) rowptr[BN_]=ex;
}

__global__ __launch_bounds__(256) void k_scatter(const int* __restrict__ src_i,
                                                 const int* __restrict__ dst_i,
                                                 const int* __restrict__ rowptr,
                                                 int* __restrict__ fill,
                                                 int* __restrict__ csr_src) {
  int idx = blockIdx.x*256+threadIdx.x;
  if (idx>=BE_) return;
  int dst = dst_i[idx];
  int pos = rowptr[dst] + atomicAdd(&fill[dst],1);
  csr_src[pos] = src_i[idx];
}

// ---------------- sa (bf16, padded to K=64) ----------------

__global__ __launch_bounds__(256) void k_sa(const float* __restrict__ ns,
                                            const int* __restrict__ a,
                                            ushort* __restrict__ sa) {
  int idx = blockIdx.x*256+threadIdx.x;
  if (idx >= BN_*64) return;
  int v = idx >> 6, c = idx & 63;
  int b = v >> 9, n = v & 511;
  float val = 0.f;
  if (c < 32)       val = ns[(size_t)b*NSROW_ + n*32 + c];
  else if (c == 32) val = (a[b]==n) ? 1.f : 0.f;
  sa[idx] = f2b(val);
}

// ---------------- LDS-tiled block-diagonal weight transpose ---------------
// 32x32 tiles: coalesced fp32 reads, coalesced bf16 writes (no strided 2B).

struct WtP { const float* Wr[4]; const float* Wn[4]; ushort* T[4]; };

__global__ __launch_bounds__(256) void k_wt_tr(WtP p) {
  int t = blockIdx.x;
  int s, base, KP, DINR, DINN, DOUTN, KOFF;
  if (t < 48)        { s=0; base=0;    KP=64;  DINR=33;  DINN=33;  DOUTN=128; KOFF=0;   }
  else if (t < 600)  { s=1; base=48;   KP=736; DINR=601; DINN=128; DOUTN=64;  KOFF=608; }
  else if (t < 1104) { s=2; base=600;  KP=672; DINR=601; DINN=64;  DOUTN=64;  KOFF=608; }
  else               { s=3; base=1104; KP=672; DINR=601; DINN=64;  DOUTN=32;  KOFF=608; }
  int ti = t - base;
  int kt = ti / 24, nt = ti - kt*24;   // 24 n-tiles (768/32) for all segments
  int k0 = kt*32, n0 = nt*32;
  __shared__ float tile[32][33];
  int tid = threadIdx.x;
  int cc = tid & 31, rr = tid >> 5;    // 8 rows per iteration
  #pragma unroll
  for (int it=0; it<4; it++) {
    int k = k0 + it*8 + rr;            // global k (padded space)
    int n = n0 + cc;                   // global combined col (0..767)
    float v = 0.f;
    if (n < 640) { if (n < 601 && k < DINR) v = p.Wr[s][(size_t)k*601 + n]; }
    else { int nn = n-640, kk = k-KOFF;
           if (nn < DOUTN && kk >= 0 && kk < DINN) v = p.Wn[s][(size_t)kk*DOUTN + nn]; }
    tile[it*8+rr][cc] = v;
  }
  __syncthreads();
  #pragma unroll
  for (int it=0; it<4; it++) {
    int n = n0 + it*8 + rr;
    int k = k0 + cc;
    p.T[s][(size_t)n*KP + k] = f2b(tile[cc][it*8+rr]);
  }
}

// ---------------- MFMA bf16 GEMM (combined heads) + fused es/ed -----------

__global__ __launch_bounds__(256) void k_gemm(const ushort* __restrict__ A,
                                              const ushort* __restrict__ Bt,
                                              ushort* __restrict__ C,
                                              float* __restrict__ esed,
                                              const float* __restrict__ asr,
                                              const float* __restrict__ adr,
                                              const float* __restrict__ asn,
                                              const float* __restrict__ adn,
                                              int Kpad, int dn) {
  __shared__ ushort Asm[128*32];
  __shared__ ushort Bsm[128*32];
  int tid = threadIdx.x;
  int rowBase = blockIdx.y * 128;
  int colBase = blockIdx.x * 128;
  int wave = tid >> 6, lane = tid & 63;
  int wr = (wave >> 1) * 64, wc = (wave & 1) * 64;
  int lm = lane & 15, lk = (lane >> 4) * 8;

  f32x4 acc[4][4];
  #pragma unroll
  for (int i=0;i<4;i++)
    #pragma unroll
    for (int j=0;j<4;j++) acc[i][j] = (f32x4){0.f,0.f,0.f,0.f};

  int t0 = tid, t1 = tid + 256;
  const ushort* Ag0 = A  + (size_t)(rowBase + (t0>>2))*Kpad + (t0&3)*8;
  const ushort* Ag1 = A  + (size_t)(rowBase + (t1>>2))*Kpad + (t1&3)*8;
  const ushort* Bg0 = Bt + (size_t)(colBase + (t0>>2))*Kpad + (t0&3)*8;
  const ushort* Bg1 = Bt + (size_t)(colBase + (t1>>2))*Kpad + (t1&3)*8;
  ushort* Al0 = &Asm[t0*8]; ushort* Al1 = &Asm[t1*8];
  ushort* Bl0 = &Bsm[t0*8]; ushort* Bl1 = &Bsm[t1*8];

  for (int k0 = 0; k0 < Kpad; k0 += 32) {
    gl_lds16(Ag0 + k0, Al0);
    gl_lds16(Ag1 + k0, Al1);
    gl_lds16(Bg0 + k0, Bl0);
    gl_lds16(Bg1 + k0, Bl1);
    __syncthreads();
    short8 af[4], bfr[4];
    #pragma unroll
    for (int i=0;i<4;i++) af[i]  = *(short8*)&Asm[(wr + i*16 + lm)*32 + lk];
    #pragma unroll
    for (int j=0;j<4;j++) bfr[j] = *(short8*)&Bsm[(wc + j*16 + lm)*32 + lk];
    #pragma unroll
    for (int i=0;i<4;i++)
      #pragma unroll
      for (int j=0;j<4;j++)
        acc[i][j] = __builtin_amdgcn_mfma_f32_16x16x32_bf16(af[i], bfr[j], acc[i][j], 0,0,0);
    __syncthreads();
  }

  float asv[4], adv[4];
  #pragma unroll
  for (int j=0;j<4;j++) {
    int col = colBase + wc + j*16 + lm;
    float s = 0.f, d = 0.f;
    if (col < 601)      { s = asr[col];     d = adr[col]; }
    else if (col >= 640 && col - 640 < dn) { s = asn[col-640]; d = adn[col-640]; }
    asv[j] = s; adv[j] = d;
  }
  int cr = lane >> 4;
  int ct2 = blockIdx.x*2 + (wc >> 6);
  #pragma unroll
  for (int i=0;i<4;i++) {
    #pragma unroll
    for (int j=0;j<4;j++) {
      int col = colBase + wc + j*16 + lm;
      #pragma unroll
      for (int g=0; g<4; g++) {
        int row = rowBase + wr + i*16 + cr*4 + g;
        C[(size_t)row*HLD_ + col] = f2b(acc[i][j][g]);
      }
    }
    #pragma unroll
    for (int g=0; g<4; g++) {
      float se = 0.f, sd = 0.f;
      #pragma unroll
      for (int j=0;j<4;j++) { se += acc[i][j][g]*asv[j]; sd += acc[i][j][g]*adv[j]; }
      #pragma unroll
      for (int o=1;o<16;o<<=1) { se += __shfl_xor(se,o,64); sd += __shfl_xor(sd,o,64); }
      if (lm == 0) {
        int row = rowBase + wr + i*16 + cr*4 + g;
        esed[(size_t)row*24 + ct2*2 + 0] = se;
        esed[(size_t)row*24 + ct2*2 + 1] = sd;
      }
    }
  }
}

// ---------------- combined softmax + aggregation (one wave per node) ------

__global__ __launch_bounds__(256) void k_agg(const ushort* __restrict__ h,
                                             const float* __restrict__ esed,
                                             const int* __restrict__ rowptr,
                                             const int* __restrict__ csr,
                                             const float* __restrict__ bias_r,
                                             const float* __restrict__ bias_n,
                                             ushort* __restrict__ g,
                                             int dn) {
  int wid = threadIdx.x>>6, lane = threadIdx.x&63;
  int bid = blockIdx.x;
  int xcd = bid & 7, slot = bid >> 3;
  int graph = xcd + ((slot >> 7) << 3);
  int v = graph*512 + (slot & 127)*4 + wid;
  int s0 = rowptr[v], e0 = rowptr[v+1];
  int deg = e0 - s0;

  float edr = 0.f, edn = 0.f;
  {
    const float* ep = esed + (size_t)v*24;
    #pragma unroll
    for (int t=0;t<10;t++) edr += ep[2*t+1];
    edn = ep[21] + ep[23];
  }

  int ch0 = lane, ch1 = lane + 64;
  bool a1 = ch1 < 96;
  float acc0[8], acc1[8];
  #pragma unroll
  for (int q=0;q<8;q++){ acc0[q]=0.f; acc1[q]=0.f; }

  if (deg <= 64) {
    bool has = lane < deg;
    int u = 0; float er = -__builtin_inff(), en = -__builtin_inff();
    if (has) {
      u = csr[s0 + lane];
      const float* ep = esed + (size_t)u*24;
      float sr = 0.f;
      #pragma unroll
      for (int t=0;t<10;t++) sr += ep[2*t];
      float sn = ep[20] + ep[22];
      er = sr + edr; er = er > 0.f ? er : 0.2f*er;
      en = sn + edn; en = en > 0.f ? en : 0.2f*en;
    }
    float mr = er, mn = en;
    #pragma unroll
    for (int o=32;o;o>>=1) { mr = fmaxf(mr, __shfl_xor(mr,o,64)); mn = fmaxf(mn, __shfl_xor(mn,o,64)); }
    float pr = has ? __expf(er - mr) : 0.f;
    float pn = has ? __expf(en - mn) : 0.f;
    float dr = pr, dnm = pn;
    #pragma unroll
    for (int o=32;o;o>>=1) { dr += __shfl_xor(dr,o,64); dnm += __shfl_xor(dnm,o,64); }
    pr *= 1.f/(dr + 1e-16f);
    pn *= 1.f/(dnm + 1e-16f);

    short8 A0{}, Bv0{}, A1{}, Bv1{};
    float w0r=0.f, w0n=0.f, w1r=0.f, w1n=0.f;
    if (deg > 0) {
      w0r = __shfl(pr, 0, 64); w0n = __shfl(pn, 0, 64); int uu = __shfl(u, 0, 64);
      const ushort* hp = h + (size_t)uu*HLD_;
      A0 = *(const short8*)&hp[ch0*8];
      if (a1) Bv0 = *(const short8*)&hp[ch1*8];
    }
    if (deg > 1) {
      w1r = __shfl(pr, 1, 64); w1n = __shfl(pn, 1, 64); int uu = __shfl(u, 1, 64);
      const ushort* hp = h + (size_t)uu*HLD_;
      A1 = *(const short8*)&hp[ch0*8];
      if (a1) Bv1 = *(const short8*)&hp[ch1*8];
    }
    bool c1r = ch1 < 80;
    for (int t = 0; t < deg; ++t) {
      short8 A2{}, Bv2{}; float w2r=0.f, w2n=0.f;
      if (t+2 < deg) {
        w2r = __shfl(pr, t+2, 64); w2n = __shfl(pn, t+2, 64); int uu = __shfl(u, t+2, 64);
        const ushort* hp = h + (size_t)uu*HLD_;
        A2 = *(const short8*)&hp[ch0*8];
        if (a1) Bv2 = *(const short8*)&hp[ch1*8];
      }
      #pragma unroll
      for (int q=0;q<8;q++) acc0[q] += w0r * b2f((ushort)A0[q]);
      if (a1) {
        float w = c1r ? w0r : w0n;
        #pragma unroll
        for (int q=0;q<8;q++) acc1[q] += w * b2f((ushort)Bv0[q]);
      }
      A0=A1; Bv0=Bv1; w0r=w1r; w0n=w1n;
      A1=A2; Bv1=Bv2; w1r=w2r; w1n=w2n;
    }
  } else {
    float mr = -__builtin_inff(), mn = -__builtin_inff();
    for (int j = s0 + lane; j < e0; j += 64) {
      const float* ep = esed + (size_t)csr[j]*24;
      float sr=0.f; for (int t=0;t<10;t++) sr += ep[2*t];
      float sn = ep[20]+ep[22];
      float er = sr + edr; er = er>0.f?er:0.2f*er;
      float en = sn + edn; en = en>0.f?en:0.2f*en;
      mr = fmaxf(mr, er); mn = fmaxf(mn, en);
    }
    #pragma unroll
    for (int o=32;o;o>>=1) { mr=fmaxf(mr,__shfl_xor(mr,o,64)); mn=fmaxf(mn,__shfl_xor(mn,o,64)); }
    float dr=0.f, dnm=0.f;
    for (int j = s0 + lane; j < e0; j += 64) {
      const float* ep = esed + (size_t)csr[j]*24;
      float sr=0.f; for (int t=0;t<10;t++) sr += ep[2*t];
      float sn = ep[20]+ep[22];
      float er = sr + edr; er = er>0.f?er:0.2f*er;
      float en = sn + edn; en = en>0.f?en:0.2f*en;
      dr += __expf(er-mr); dnm += __expf(en-mn);
    }
    #pragma unroll
    for (int o=32;o;o>>=1) { dr+=__shfl_xor(dr,o,64); dnm+=__shfl_xor(dnm,o,64); }
    float ir = 1.f/(dr+1e-16f), in_ = 1.f/(dnm+1e-16f);
    bool c1r = ch1 < 80;
    for (int j = s0; j < e0; ++j) {
      int uu = csr[j];
      const float* ep = esed + (size_t)uu*24;
      float sr=0.f; for (int t=0;t<10;t++) sr += ep[2*t];
      float sn = ep[20]+ep[22];
      float er = sr + edr; er = er>0.f?er:0.2f*er;
      float en = sn + edn; en = en>0.f?en:0.2f*en;
      float wr2 = __expf(er-mr)*ir, wn2 = __expf(en-mn)*in_;
      const ushort* hp = h + (size_t)uu*HLD_;
      short8 hv = *(const short8*)&hp[ch0*8];
      #pragma unroll
      for (int q=0;q<8;q++) acc0[q] += wr2 * b2f((ushort)hv[q]);
      if (a1) {
        short8 hv2 = *(const short8*)&hp[ch1*8];
        float w = c1r ? wr2 : wn2;
        #pragma unroll
        for (int q=0;q<8;q++) acc1[q] += w * b2f((ushort)hv2[q]);
      }
    }
  }

  ushort* gv = g + (size_t)v*HLD_;
  {
    int cb = ch0*8;
    short8 ov;
    #pragma unroll
    for (int q=0;q<8;q++) ov[q] = (short)f2b(acc0[q] + bias_r[cb+q]);
    *(short8*)&gv[cb] = ov;
  }
  if (a1) {
    int cb = ch1*8;
    short8 ov;
    #pragma unroll
    for (int q=0;q<8;q++) {
      int c = cb+q;
      float val;
      if (c < 601)                         val = acc1[q] + bias_r[c];
      else if (c >= 640 && (c-640) < dn)   val = acc1[q] + bias_n[c-640];
      else                                 val = 0.f;
      ov[q] = (short)f2b(val);
    }
    *(short8*)&gv[cb] = ov;
  }
}

// ---------------- LN stats partials over all 768 cols ----------------

__global__ __launch_bounds__(256) void k_ln_stats(const ushort* __restrict__ g,
                                                  float* __restrict__ st) {
  int b = blockIdx.y, z = blockIdx.z; int n0 = z*64;
  int lc = threadIdx.x & 63, r0 = threadIdx.x >> 6;
  int c = blockIdx.x*64 + lc;
  float s=0.f, q=0.f;
  #pragma unroll 4
  for (int i=0;i<16;i++) {
    int n = n0 + r0*16 + i;
    float x = b2f(g[(size_t)(b*N_+n)*HLD_ + c]);
    s+=x; q+=x*x;
  }
  __shared__ float S[4][64], Q[4][64];
  S[r0][lc]=s; Q[r0][lc]=q; __syncthreads();
  if (r0==0) {
    st[((size_t)(z*2+0)*B_ + b)*HLD_ + c] = S[0][lc]+S[1][lc]+S[2][lc]+S[3][lc];
    st[((size_t)(z*2+1)*B_ + b)*HLD_ + c] = Q[0][lc]+Q[1][lc]+Q[2][lc]+Q[3][lc];
  }
}

// ---------------- LN apply + ReLU (finalize folded in; thread owns col pair
// for 16 rows of one graph: 32 stat loads amortized over 32 outputs) --------

__global__ __launch_bounds__(256) void k_ln_apply(const ushort* __restrict__ g,
                                                  const float* __restrict__ st,
                                                  const float* __restrict__ scr,
                                                  const float* __restrict__ ofr,
                                                  const float* __restrict__ scn,
                                                  const float* __restrict__ ofn,
                                                  ushort* __restrict__ xb,
                                                  int dn, int Kpad) {
  int tid = threadIdx.x;
  int pp = blockIdx.x*128 + (tid & 127);
  int c0 = pp*2;
  if (c0 >= Kpad) return;
  int vbase = blockIdx.y*16;
  int b = vbase >> 9;
  float mv[2], av[2];
  #pragma unroll
  for (int q=0;q<2;q++) {
    int c = c0+q;
    int cs; bool valid; float scale, offs;
    if (c < 608) { cs = c; valid = c < 601;
                   scale = valid ? scr[c] : 0.f; offs = valid ? ofr[c] : 0.f; }
    else { int cn = c - 608; cs = 640 + cn; valid = cn < dn;
           scale = valid ? scn[cn] : 0.f; offs = valid ? ofn[cn] : 0.f; }
    float mul = 0.f, add = 0.f;
    if (valid) {
      float s=0.f, qq=0.f;
      #pragma unroll
      for (int z=0;z<8;z++) {
        s  += st[((size_t)(z*2+0)*B_ + b)*HLD_ + cs];
        qq += st[((size_t)(z*2+1)*B_ + b)*HLD_ + cs];
      }
      float mu = s*(1.f/N_);
      float var = qq*(1.f/N_) - mu*mu;
      float rs = rsqrtf(var+1e-5f);
      mul = rs*scale;
      add = offs - mu*rs*scale;
    }
    mv[q] = mul; av[q] = add;
  }
  int cs0 = (c0 < 608) ? c0 : 640 + (c0 - 608);
  for (int i = tid >> 7; i < 16; i += 2) {
    int v = vbase + i;
    uint gg = *(const uint*)&g[(size_t)v*HLD_ + cs0];
    float x0 = b2f((ushort)(gg & 0xFFFFu));
    float x1 = b2f((ushort)(gg >> 16));
    float y0 = x0*mv[0] + av[0]; y0 = y0 > 0.f ? y0 : 0.f;
    float y1 = x1*mv[1] + av[1]; y1 = y1 > 0.f ? y1 : 0.f;
    *(uint*)&xb[(size_t)v*Kpad + c0] = ((uint)f2b(y1) << 16) | f2b(y0);
  }
}

// ---------------- reward: sum over nodes (slot partials) ----------------

__global__ __launch_bounds__(256) void k_rsum(const ushort* __restrict__ g,
                                              float* __restrict__ rsp) {
  int b = blockIdx.y, z = blockIdx.z; int n0 = z*64;
  int lc = threadIdx.x & 63, r0 = threadIdx.x>>6;
  int c = blockIdx.x*64 + lc;
  float s = 0.f;
  if (c < FSS_) {
    #pragma unroll 4
    for (int i=0;i<16;i++) {
      int n = n0 + r0*16 + i;
      s += b2f(g[(size_t)(b*N_+n)*HLD_ + c]);
    }
  }
  __shared__ float S[4][64];
  S[r0][lc]=s; __syncthreads();
  if (r0==0 && c<FSS_)
    rsp[((size_t)z*B_ + b)*FSS_ + c] = S[0][lc]+S[1][lc]+S[2][lc]+S[3][lc];
}

// ---------------- final: reward finalize + ns_new assembly ----------------

__global__ __launch_bounds__(256) void k_final(const float* __restrict__ rsp,
                                               const ushort* __restrict__ g,
                                               const float* __restrict__ ns,
                                               float* __restrict__ out) {
  int idx = blockIdx.x*256+threadIdx.x;
  if (idx < OUT_R_) {
    int b = idx / FSS_, c = idx - b*FSS_;
    float s = 0.f;
    #pragma unroll
    for (int z=0;z<8;z++) s += rsp[((size_t)z*B_ + b)*FSS_ + c];
    out[idx] = s;
  } else {
    int j2 = idx - OUT_R_;
    if (j2 >= B_*NSROW_) return;
    int b = j2 / NSROW_; int j = j2 - b*NSROW_;
    float v;
    if (j < SLEFT_) {
      int n = j >> 5, c = j & 31;
      v = b2f(g[(size_t)(b*N_+n)*HLD_ + 640 + c]);
    } else {
      v = ns[(size_t)b*NSROW_ + j];
    }
    out[idx] = v;
  }
}

// ---------------- host driver ----------------

extern "C" void kernel_launch(void* const* d_in, const int* in_sizes, int n_in,
                              void* d_out, int out_size, void* d_ws, size_t ws_size,
                              hipStream_t stream) {
  const float* ns = (const float*)d_in[0];
  const int*   a  = (const int*)d_in[1];

  const float *W[4], *As[4], *Ad[4], *Bb[4], *Sc[3], *Of[3];
  const float *rW[4], *rAs[4], *rAd[4], *rBb[4], *rSc[3], *rOf[3];
  int p = 2;
  for (int i=0;i<4;i++){
    W[i]=(const float*)d_in[p++]; As[i]=(const float*)d_in[p++];
    Ad[i]=(const float*)d_in[p++]; Bb[i]=(const float*)d_in[p++];
    if (i<3){ Sc[i]=(const float*)d_in[p++]; Of[i]=(const float*)d_in[p++]; }
  }
  for (int i=0;i<4;i++){
    rW[i]=(const float*)d_in[p++]; rAs[i]=(const float*)d_in[p++];
    rAd[i]=(const float*)d_in[p++]; rBb[i]=(const float*)d_in[p++];
    if (i<3){ rSc[i]=(const float*)d_in[p++]; rOf[i]=(const float*)d_in[p++]; }
  }

  char* w = (char*)d_ws;
  auto carve = [&](size_t bytes)->void* {
    void* r = (void*)w;
    w += (bytes + 255) & ~(size_t)255;
    return r;
  };
  ushort* xb   = (ushort*)carve((size_t)BN_*736*2);
  ushort* hbuf = (ushort*)carve((size_t)BN_*HLD_*2);
  ushort* gbuf = (ushort*)carve((size_t)BN_*HLD_*2);
  ushort* sabf = (ushort*)carve((size_t)BN_*64*2);
  float* esed  = (float*)carve((size_t)BN_*24*4);
  float* stp   = (float*)carve((size_t)16*B_*HLD_*4);
  float* rsp   = (float*)carve((size_t)8*B_*FSS_*4);
  int* src_i   = (int*)carve((size_t)BE_*4);
  int* dst_i   = (int*)carve((size_t)BE_*4);
  int* cnt     = (int*)carve((size_t)2*BN_*4);   // cnt | fill contiguous
  int* fill    = cnt + BN_;
  int* rowptr  = (int*)carve((size_t)(BN_+1)*4);
  int* csr_src = (int*)carve((size_t)BE_*4);
  ushort* Wt[4];
  Wt[0] = (ushort*)carve((size_t)768*64*2);
  Wt[1] = (ushort*)carve((size_t)768*736*2);
  Wt[2] = (ushort*)carve((size_t)768*672*2);
  Wt[3] = (ushort*)carve((size_t)768*672*2);

  float* out = (float*)d_out;

  hipMemsetAsync(cnt, 0, (size_t)2*BN_*4, stream);

  k_indices<<<(BE_+255)/256, 256, 0, stream>>>(ns, src_i, dst_i, cnt);
  k_scan<<<1, 1024, 0, stream>>>(cnt, rowptr);
  k_scatter<<<(BE_+255)/256, 256, 0, stream>>>(src_i, dst_i, rowptr, fill, csr_src);
  k_sa<<<(BN_*64+255)/256, 256, 0, stream>>>(ns, a, sabf);

  WtP wtp;
  for (int i=0;i<4;i++){ wtp.Wr[i]=rW[i]; wtp.Wn[i]=W[i]; wtp.T[i]=Wt[i]; }
  k_wt_tr<<<1608, 256, 0, stream>>>(wtp);

  dim3 ggrid(6, BN_/128);

  // L1: K=64 (shared sa), dn=128
  k_gemm<<<ggrid, 256, 0, stream>>>(sabf, Wt[0], hbuf, esed, rAs[0],rAd[0],As[0],Ad[0], 64, 128);
  k_agg<<<BN_/4, 256, 0, stream>>>(hbuf, esed, rowptr, csr_src, rBb[0], Bb[0], gbuf, 128);
  k_ln_stats<<<dim3(12, B_, 8), 256, 0, stream>>>(gbuf, stp);
  k_ln_apply<<<dim3(3, BN_/16), 256, 0, stream>>>(gbuf, stp, rSc[0],rOf[0],Sc[0],Of[0], xb, 128, 736);

  // L2: K=736, dn=64
  k_gemm<<<ggrid, 256, 0, stream>>>(xb, Wt[1], hbuf, esed, rAs[1],rAd[1],As[1],Ad[1], 736, 64);
  k_agg<<<BN_/4, 256, 0, stream>>>(hbuf, esed, rowptr, csr_src, rBb[1], Bb[1], gbuf, 64);
  k_ln_stats<<<dim3(12, B_, 8), 256, 0, stream>>>(gbuf, stp);
  k_ln_apply<<<dim3(3, BN_/16), 256, 0, stream>>>(gbuf, stp, rSc[1],rOf[1],Sc[1],Of[1], xb, 64, 672);

  // L3: K=672, dn=64
  k_gemm<<<ggrid, 256, 0, stream>>>(xb, Wt[2], hbuf, esed, rAs[2],rAd[2],As[2],Ad[2], 672, 64);
  k_agg<<<BN_/4, 256, 0, stream>>>(hbuf, esed, rowptr, csr_src, rBb[2], Bb[2], gbuf, 64);
  k_ln_stats<<<dim3(12, B_, 8), 256, 0, stream>>>(gbuf, stp);
  k_ln_apply<<<dim3(3, BN_/16), 256, 0, stream>>>(gbuf, stp, rSc[2],rOf[2],Sc[2],Of[2], xb, 64, 672);

  // L4: K=672, dn=32, no LN
  k_gemm<<<ggrid, 256, 0, stream>>>(xb, Wt[3], hbuf, esed, rAs[3],rAd[3],As[3],Ad[3], 672, 32);
  k_agg<<<BN_/4, 256, 0, stream>>>(hbuf, esed, rowptr, csr_src, rBb[3], Bb[3], gbuf, 32);

  k_rsum<<<dim3(10, B_, 8), 256, 0, stream>>>(gbuf, rsp);
  k_final<<<(OUT_R_ + B_*NSROW_ + 255)/256, 256, 0, stream>>>(rsp, gbuf, ns, out);
}

// Round 9
// 409.579 us; speedup vs baseline: 1.4923x; 1.0178x over previous
//
#include <hip/hip_runtime.h>
#include <math.h>

#define B_ 16
#define N_ 512
#define D_ 32
#define E_ 8176
#define SLEFT_ 16384
#define FSS_ 601
#define BN_ (B_*N_)            // 8192
#define BE_ (B_*E_)            // 130816
#define NSROW_ (SLEFT_ + 2*E_) // 32736
#define OUT_R_ (B_*FSS_)       // 9616
#define HLD_ 768               // combined h width: reward 0..639, next 640..767

typedef __attribute__((ext_vector_type(8))) short short8;
typedef __attribute__((ext_vector_type(4))) float f32x4;

typedef __attribute__((address_space(3))) uint lds_uint;
typedef __attribute__((address_space(1))) const uint g_uint;

__device__ __forceinline__ void gl_lds16(const ushort* gp, ushort* lp) {
  __builtin_amdgcn_global_load_lds((g_uint*)gp, (lds_uint*)lp, 16, 0, 0);
}

__device__ __forceinline__ ushort f2b(float f) {
  uint u = __builtin_bit_cast(uint, f);
  u += 0x7FFFu + ((u >> 16) & 1u);
  return (ushort)(u >> 16);
}
__device__ __forceinline__ float b2f(ushort h) {
  return __builtin_bit_cast(float, ((uint)h) << 16);
}

// ---------------- index / CSR build ----------------

__global__ __launch_bounds__(256) void k_indices(const float* __restrict__ ns,
                                                 int* __restrict__ src_i,
                                                 int* __restrict__ dst_i,
                                                 int* __restrict__ cnt) {
  int idx = blockIdx.x*256 + threadIdx.x;
  if (idx >= BE_) return;
  int b = idx / E_;
  int j = idx - b*E_;
  const float* row = ns + (size_t)b*NSROW_;
  int s = (int)row[SLEFT_ + j];
  int r = (int)row[SLEFT_ + E_ + j];
  src_i[idx] = b*N_ + s;
  int dst = b*N_ + r;
  dst_i[idx] = dst;
  atomicAdd(&cnt[dst], 1);
}

__global__ __launch_bounds__(1024) void k_scan(const int* __restrict__ cnt,
                                               int* __restrict__ rowptr) {
  __shared__ int part[1024];
  int t = threadIdx.x;
  int base = t*8;
  int loc[8]; int s = 0;
  #pragma unroll
  for (int i=0;i<8;i++){ loc[i]=cnt[base+i]; s+=loc[i]; }
  part[t]=s; __syncthreads();
  for (int off=1; off<1024; off<<=1) {
    int v = (t>=off)?part[t-off]:0;
    __syncthreads();
    part[t]+=v;
    __syncthreads();
  }
  int ex = (t==0)?0:part[t-1];
  #pragma unroll
  for (int i=0;i<8;i++){ rowptr[base+i]=ex; ex+=loc[i]; }
  if (t==1023) rowptr[BN_]=ex;
}

__global__ __launch_bounds__(256) void k_scatter(const int* __restrict__ src_i,
                                                 const int* __restrict__ dst_i,
                                                 const int* __restrict__ rowptr,
                                                 int* __restrict__ fill,
                                                 int* __restrict__ csr_src) {
  int idx = blockIdx.x*256+threadIdx.x;
  if (idx>=BE_) return;
  int dst = dst_i[idx];
  int pos = rowptr[dst] + atomicAdd(&fill[dst],1);
  csr_src[pos] = src_i[idx];
}

// ---------------- sa (bf16, padded to K=64) ----------------

__global__ __launch_bounds__(256) void k_sa(const float* __restrict__ ns,
                                            const int* __restrict__ a,
                                            ushort* __restrict__ sa) {
  int idx = blockIdx.x*256+threadIdx.x;
  if (idx >= BN_*64) return;
  int v = idx >> 6, c = idx & 63;
  int b = v >> 9, n = v & 511;
  float val = 0.f;
  if (c < 32)       val = ns[(size_t)b*NSROW_ + n*32 + c];
  else if (c == 32) val = (a[b]==n) ? 1.f : 0.f;
  sa[idx] = f2b(val);
}

// ---------------- LDS-tiled block-diagonal weight transpose ---------------

struct WtP { const float* Wr[4]; const float* Wn[4]; ushort* T[4]; };

__global__ __launch_bounds__(256) void k_wt_tr(WtP p) {
  int t = blockIdx.x;
  int s, base, KP, DINR, DINN, DOUTN, KOFF;
  if (t < 48)        { s=0; base=0;    KP=64;  DINR=33;  DINN=33;  DOUTN=128; KOFF=0;   }
  else if (t < 600)  { s=1; base=48;   KP=736; DINR=601; DINN=128; DOUTN=64;  KOFF=608; }
  else if (t < 1104) { s=2; base=600;  KP=672; DINR=601; DINN=64;  DOUTN=64;  KOFF=608; }
  else               { s=3; base=1104; KP=672; DINR=601; DINN=64;  DOUTN=32;  KOFF=608; }
  int ti = t - base;
  int kt = ti / 24, nt = ti - kt*24;
  int k0 = kt*32, n0 = nt*32;
  __shared__ float tile[32][33];
  int tid = threadIdx.x;
  int cc = tid & 31, rr = tid >> 5;
  #pragma unroll
  for (int it=0; it<4; it++) {
    int k = k0 + it*8 + rr;
    int n = n0 + cc;
    float v = 0.f;
    if (n < 640) { if (n < 601 && k < DINR) v = p.Wr[s][(size_t)k*601 + n]; }
    else { int nn = n-640, kk = k-KOFF;
           if (nn < DOUTN && kk >= 0 && kk < DINN) v = p.Wn[s][(size_t)kk*DOUTN + nn]; }
    tile[it*8+rr][cc] = v;
  }
  __syncthreads();
  #pragma unroll
  for (int it=0; it<4; it++) {
    int n = n0 + it*8 + rr;
    int k = k0 + cc;
    p.T[s][(size_t)n*KP + k] = f2b(tile[cc][it*8+rr]);
  }
}

// ---------------- MFMA bf16 GEMM, 64x128 tile (combined heads) + es/ed ----
// grid (6, 128) = 768 blocks (~3/CU). 4 waves, each 32 rows x 64 cols.

__global__ __launch_bounds__(256) void k_gemm(const ushort* __restrict__ A,
                                              const ushort* __restrict__ Bt,
                                              ushort* __restrict__ C,
                                              float* __restrict__ esed,
                                              const float* __restrict__ asr,
                                              const float* __restrict__ adr,
                                              const float* __restrict__ asn,
                                              const float* __restrict__ adn,
                                              int Kpad, int dn) {
  __shared__ ushort Asm[64*32];
  __shared__ ushort Bsm[128*32];
  int tid = threadIdx.x;
  int rowBase = blockIdx.y * 64;
  int colBase = blockIdx.x * 128;
  int wave = tid >> 6, lane = tid & 63;
  int wr = (wave >> 1) * 32, wc = (wave & 1) * 64;
  int lm = lane & 15, lk = (lane >> 4) * 8;

  f32x4 acc[2][4];
  #pragma unroll
  for (int i=0;i<2;i++)
    #pragma unroll
    for (int j=0;j<4;j++) acc[i][j] = (f32x4){0.f,0.f,0.f,0.f};

  int t0 = tid, t1 = tid + 256;
  const ushort* Ag0 = A  + (size_t)(rowBase + (t0>>2))*Kpad + (t0&3)*8;
  const ushort* Bg0 = Bt + (size_t)(colBase + (t0>>2))*Kpad + (t0&3)*8;
  const ushort* Bg1 = Bt + (size_t)(colBase + (t1>>2))*Kpad + (t1&3)*8;
  ushort* Al0 = &Asm[t0*8];
  ushort* Bl0 = &Bsm[t0*8];
  ushort* Bl1 = &Bsm[t1*8];

  for (int k0 = 0; k0 < Kpad; k0 += 32) {
    gl_lds16(Ag0 + k0, Al0);
    gl_lds16(Bg0 + k0, Bl0);
    gl_lds16(Bg1 + k0, Bl1);
    __syncthreads();
    short8 af[2], bfr[4];
    #pragma unroll
    for (int i=0;i<2;i++) af[i]  = *(short8*)&Asm[(wr + i*16 + lm)*32 + lk];
    #pragma unroll
    for (int j=0;j<4;j++) bfr[j] = *(short8*)&Bsm[(wc + j*16 + lm)*32 + lk];
    #pragma unroll
    for (int i=0;i<2;i++)
      #pragma unroll
      for (int j=0;j<4;j++)
        acc[i][j] = __builtin_amdgcn_mfma_f32_16x16x32_bf16(af[i], bfr[j], acc[i][j], 0,0,0);
    __syncthreads();
  }

  float asv[4], adv[4];
  #pragma unroll
  for (int j=0;j<4;j++) {
    int col = colBase + wc + j*16 + lm;
    float s = 0.f, d = 0.f;
    if (col < 601)      { s = asr[col];     d = adr[col]; }
    else if (col >= 640 && col - 640 < dn) { s = asn[col-640]; d = adn[col-640]; }
    asv[j] = s; adv[j] = d;
  }
  int cr = lane >> 4;
  int ct2 = blockIdx.x*2 + (wc >> 6);
  #pragma unroll
  for (int i=0;i<2;i++) {
    #pragma unroll
    for (int j=0;j<4;j++) {
      int col = colBase + wc + j*16 + lm;
      #pragma unroll
      for (int g=0; g<4; g++) {
        int row = rowBase + wr + i*16 + cr*4 + g;
        C[(size_t)row*HLD_ + col] = f2b(acc[i][j][g]);
      }
    }
    #pragma unroll
    for (int g=0; g<4; g++) {
      float se = 0.f, sd = 0.f;
      #pragma unroll
      for (int j=0;j<4;j++) { se += acc[i][j][g]*asv[j]; sd += acc[i][j][g]*adv[j]; }
      #pragma unroll
      for (int o=1;o<16;o<<=1) { se += __shfl_xor(se,o,64); sd += __shfl_xor(sd,o,64); }
      if (lm == 0) {
        int row = rowBase + wr + i*16 + cr*4 + g;
        esed[(size_t)row*24 + ct2*2 + 0] = se;
        esed[(size_t)row*24 + ct2*2 + 1] = sd;
      }
    }
  }
}

// ---------------- combined softmax + aggregation (one wave per node) ------

__global__ __launch_bounds__(256) void k_agg(const ushort* __restrict__ h,
                                             const float* __restrict__ esed,
                                             const int* __restrict__ rowptr,
                                             const int* __restrict__ csr,
                                             const float* __restrict__ bias_r,
                                             const float* __restrict__ bias_n,
                                             ushort* __restrict__ g,
                                             int dn) {
  int wid = threadIdx.x>>6, lane = threadIdx.x&63;
  int bid = blockIdx.x;
  int xcd = bid & 7, slot = bid >> 3;
  int graph = xcd + ((slot >> 7) << 3);
  int v = graph*512 + (slot & 127)*4 + wid;
  int s0 = rowptr[v], e0 = rowptr[v+1];
  int deg = e0 - s0;

  float edr = 0.f, edn = 0.f;
  {
    const float* ep = esed + (size_t)v*24;
    #pragma unroll
    for (int t=0;t<10;t++) edr += ep[2*t+1];
    edn = ep[21] + ep[23];
  }

  int ch0 = lane, ch1 = lane + 64;
  bool a1 = ch1 < 96;
  float acc0[8], acc1[8];
  #pragma unroll
  for (int q=0;q<8;q++){ acc0[q]=0.f; acc1[q]=0.f; }

  if (deg <= 64) {
    bool has = lane < deg;
    int u = 0; float er = -__builtin_inff(), en = -__builtin_inff();
    if (has) {
      u = csr[s0 + lane];
      const float* ep = esed + (size_t)u*24;
      float sr = 0.f;
      #pragma unroll
      for (int t=0;t<10;t++) sr += ep[2*t];
      float sn = ep[20] + ep[22];
      er = sr + edr; er = er > 0.f ? er : 0.2f*er;
      en = sn + edn; en = en > 0.f ? en : 0.2f*en;
    }
    float mr = er, mn = en;
    #pragma unroll
    for (int o=32;o;o>>=1) { mr = fmaxf(mr, __shfl_xor(mr,o,64)); mn = fmaxf(mn, __shfl_xor(mn,o,64)); }
    float pr = has ? __expf(er - mr) : 0.f;
    float pn = has ? __expf(en - mn) : 0.f;
    float dr = pr, dnm = pn;
    #pragma unroll
    for (int o=32;o;o>>=1) { dr += __shfl_xor(dr,o,64); dnm += __shfl_xor(dnm,o,64); }
    pr *= 1.f/(dr + 1e-16f);
    pn *= 1.f/(dnm + 1e-16f);

    short8 A0{}, Bv0{}, A1{}, Bv1{};
    float w0r=0.f, w0n=0.f, w1r=0.f, w1n=0.f;
    if (deg > 0) {
      w0r = __shfl(pr, 0, 64); w0n = __shfl(pn, 0, 64); int uu = __shfl(u, 0, 64);
      const ushort* hp = h + (size_t)uu*HLD_;
      A0 = *(const short8*)&hp[ch0*8];
      if (a1) Bv0 = *(const short8*)&hp[ch1*8];
    }
    if (deg > 1) {
      w1r = __shfl(pr, 1, 64); w1n = __shfl(pn, 1, 64); int uu = __shfl(u, 1, 64);
      const ushort* hp = h + (size_t)uu*HLD_;
      A1 = *(const short8*)&hp[ch0*8];
      if (a1) Bv1 = *(const short8*)&hp[ch1*8];
    }
    bool c1r = ch1 < 80;
    for (int t = 0; t < deg; ++t) {
      short8 A2{}, Bv2{}; float w2r=0.f, w2n=0.f;
      if (t+2 < deg) {
        w2r = __shfl(pr, t+2, 64); w2n = __shfl(pn, t+2, 64); int uu = __shfl(u, t+2, 64);
        const ushort* hp = h + (size_t)uu*HLD_;
        A2 = *(const short8*)&hp[ch0*8];
        if (a1) Bv2 = *(const short8*)&hp[ch1*8];
      }
      #pragma unroll
      for (int q=0;q<8;q++) acc0[q] += w0r * b2f((ushort)A0[q]);
      if (a1) {
        float w = c1r ? w0r : w0n;
        #pragma unroll
        for (int q=0;q<8;q++) acc1[q] += w * b2f((ushort)Bv0[q]);
      }
      A0=A1; Bv0=Bv1; w0r=w1r; w0n=w1n;
      A1=A2; Bv1=Bv2; w1r=w2r; w1n=w2n;
    }
  } else {
    float mr = -__builtin_inff(), mn = -__builtin_inff();
    for (int j = s0 + lane; j < e0; j += 64) {
      const float* ep = esed + (size_t)csr[j]*24;
      float sr=0.f; for (int t=0;t<10;t++) sr += ep[2*t];
      float sn = ep[20]+ep[22];
      float er = sr + edr; er = er>0.f?er:0.2f*er;
      float en = sn + edn; en = en>0.f?en:0.2f*en;
      mr = fmaxf(mr, er); mn = fmaxf(mn, en);
    }
    #pragma unroll
    for (int o=32;o;o>>=1) { mr=fmaxf(mr,__shfl_xor(mr,o,64)); mn=fmaxf(mn,__shfl_xor(mn,o,64)); }
    float dr=0.f, dnm=0.f;
    for (int j = s0 + lane; j < e0; j += 64) {
      const float* ep = esed + (size_t)csr[j]*24;
      float sr=0.f; for (int t=0;t<10;t++) sr += ep[2*t];
      float sn = ep[20]+ep[22];
      float er = sr + edr; er = er>0.f?er:0.2f*er;
      float en = sn + edn; en = en>0.f?en:0.2f*en;
      dr += __expf(er-mr); dnm += __expf(en-mn);
    }
    #pragma unroll
    for (int o=32;o;o>>=1) { dr+=__shfl_xor(dr,o,64); dnm+=__shfl_xor(dnm,o,64); }
    float ir = 1.f/(dr+1e-16f), in_ = 1.f/(dnm+1e-16f);
    bool c1r = ch1 < 80;
    for (int j = s0; j < e0; ++j) {
      int uu = csr[j];
      const float* ep = esed + (size_t)uu*24;
      float sr=0.f; for (int t=0;t<10;t++) sr += ep[2*t];
      float sn = ep[20]+ep[22];
      float er = sr + edr; er = er>0.f?er:0.2f*er;
      float en = sn + edn; en = en>0.f?en:0.2f*en;
      float wr2 = __expf(er-mr)*ir, wn2 = __expf(en-mn)*in_;
      const ushort* hp = h + (size_t)uu*HLD_;
      short8 hv = *(const short8*)&hp[ch0*8];
      #pragma unroll
      for (int q=0;q<8;q++) acc0[q] += wr2 * b2f((ushort)hv[q]);
      if (a1) {
        short8 hv2 = *(const short8*)&hp[ch1*8];
        float w = c1r ? wr2 : wn2;
        #pragma unroll
        for (int q=0;q<8;q++) acc1[q] += w * b2f((ushort)hv2[q]);
      }
    }
  }

  ushort* gv = g + (size_t)v*HLD_;
  {
    int cb = ch0*8;
    short8 ov;
    #pragma unroll
    for (int q=0;q<8;q++) ov[q] = (short)f2b(acc0[q] + bias_r[cb+q]);
    *(short8*)&gv[cb] = ov;
  }
  if (a1) {
    int cb = ch1*8;
    short8 ov;
    #pragma unroll
    for (int q=0;q<8;q++) {
      int c = cb+q;
      float val;
      if (c < 601)                         val = acc1[q] + bias_r[c];
      else if (c >= 640 && (c-640) < dn)   val = acc1[q] + bias_n[c-640];
      else                                 val = 0.f;
      ov[q] = (short)f2b(val);
    }
    *(short8*)&gv[cb] = ov;
  }
}

// ---------------- LN stats partials over all 768 cols ----------------

__global__ __launch_bounds__(256) void k_ln_stats(const ushort* __restrict__ g,
                                                  float* __restrict__ st) {
  int b = blockIdx.y, z = blockIdx.z; int n0 = z*64;
  int lc = threadIdx.x & 63, r0 = threadIdx.x >> 6;
  int c = blockIdx.x*64 + lc;
  float s=0.f, q=0.f;
  #pragma unroll 4
  for (int i=0;i<16;i++) {
    int n = n0 + r0*16 + i;
    float x = b2f(g[(size_t)(b*N_+n)*HLD_ + c]);
    s+=x; q+=x*x;
  }
  __shared__ float S[4][64], Q[4][64];
  S[r0][lc]=s; Q[r0][lc]=q; __syncthreads();
  if (r0==0) {
    st[((size_t)(z*2+0)*B_ + b)*HLD_ + c] = S[0][lc]+S[1][lc]+S[2][lc]+S[3][lc];
    st[((size_t)(z*2+1)*B_ + b)*HLD_ + c] = Q[0][lc]+Q[1][lc]+Q[2][lc]+Q[3][lc];
  }
}

// ---------------- LN apply + ReLU (finalize folded; col pair x 16 rows) ---

__global__ __launch_bounds__(256) void k_ln_apply(const ushort* __restrict__ g,
                                                  const float* __restrict__ st,
                                                  const float* __restrict__ scr,
                                                  const float* __restrict__ ofr,
                                                  const float* __restrict__ scn,
                                                  const float* __restrict__ ofn,
                                                  ushort* __restrict__ xb,
                                                  int dn, int Kpad) {
  int tid = threadIdx.x;
  int pp = blockIdx.x*128 + (tid & 127);
  int c0 = pp*2;
  if (c0 >= Kpad) return;
  int vbase = blockIdx.y*16;
  int b = vbase >> 9;
  float mv[2], av[2];
  #pragma unroll
  for (int q=0;q<2;q++) {
    int c = c0+q;
    int cs; bool valid; float scale, offs;
    if (c < 608) { cs = c; valid = c < 601;
                   scale = valid ? scr[c] : 0.f; offs = valid ? ofr[c] : 0.f; }
    else { int cn = c - 608; cs = 640 + cn; valid = cn < dn;
           scale = valid ? scn[cn] : 0.f; offs = valid ? ofn[cn] : 0.f; }
    float mul = 0.f, add = 0.f;
    if (valid) {
      float s=0.f, qq=0.f;
      #pragma unroll
      for (int z=0;z<8;z++) {
        s  += st[((size_t)(z*2+0)*B_ + b)*HLD_ + cs];
        qq += st[((size_t)(z*2+1)*B_ + b)*HLD_ + cs];
      }
      float mu = s*(1.f/N_);
      float var = qq*(1.f/N_) - mu*mu;
      float rs = rsqrtf(var+1e-5f);
      mul = rs*scale;
      add = offs - mu*rs*scale;
    }
    mv[q] = mul; av[q] = add;
  }
  int cs0 = (c0 < 608) ? c0 : 640 + (c0 - 608);
  for (int i = tid >> 7; i < 16; i += 2) {
    int v = vbase + i;
    uint gg = *(const uint*)&g[(size_t)v*HLD_ + cs0];
    float x0 = b2f((ushort)(gg & 0xFFFFu));
    float x1 = b2f((ushort)(gg >> 16));
    float y0 = x0*mv[0] + av[0]; y0 = y0 > 0.f ? y0 : 0.f;
    float y1 = x1*mv[1] + av[1]; y1 = y1 > 0.f ? y1 : 0.f;
    *(uint*)&xb[(size_t)v*Kpad + c0] = ((uint)f2b(y1) << 16) | f2b(y0);
  }
}

// ---------------- reward: sum over nodes (slot partials) ----------------

__global__ __launch_bounds__(256) void k_rsum(const ushort* __restrict__ g,
                                              float* __restrict__ rsp) {
  int b = blockIdx.y, z = blockIdx.z; int n0 = z*64;
  int lc = threadIdx.x & 63, r0 = threadIdx.x>>6;
  int c = blockIdx.x*64 + lc;
  float s = 0.f;
  if (c < FSS_) {
    #pragma unroll 4
    for (int i=0;i<16;i++) {
      int n = n0 + r0*16 + i;
      s += b2f(g[(size_t)(b*N_+n)*HLD_ + c]);
    }
  }
  __shared__ float S[4][64];
  S[r0][lc]=s; __syncthreads();
  if (r0==0 && c<FSS_)
    rsp[((size_t)z*B_ + b)*FSS_ + c] = S[0][lc]+S[1][lc]+S[2][lc]+S[3][lc];
}

// ---------------- final: reward finalize + ns_new assembly ----------------

__global__ __launch_bounds__(256) void k_final(const float* __restrict__ rsp,
                                               const ushort* __restrict__ g,
                                               const float* __restrict__ ns,
                                               float* __restrict__ out) {
  int idx = blockIdx.x*256+threadIdx.x;
  if (idx < OUT_R_) {
    int b = idx / FSS_, c = idx - b*FSS_;
    float s = 0.f;
    #pragma unroll
    for (int z=0;z<8;z++) s += rsp[((size_t)z*B_ + b)*FSS_ + c];
    out[idx] = s;
  } else {
    int j2 = idx - OUT_R_;
    if (j2 >= B_*NSROW_) return;
    int b = j2 / NSROW_; int j = j2 - b*NSROW_;
    float v;
    if (j < SLEFT_) {
      int n = j >> 5, c = j & 31;
      v = b2f(g[(size_t)(b*N_+n)*HLD_ + 640 + c]);
    } else {
      v = ns[(size_t)b*NSROW_ + j];
    }
    out[idx] = v;
  }
}

// ---------------- host driver ----------------

extern "C" void kernel_launch(void* const* d_in, const int* in_sizes, int n_in,
                              void* d_out, int out_size, void* d_ws, size_t ws_size,
                              hipStream_t stream) {
  const float* ns = (const float*)d_in[0];
  const int*   a  = (const int*)d_in[1];

  const float *W[4], *As[4], *Ad[4], *Bb[4], *Sc[3], *Of[3];
  const float *rW[4], *rAs[4], *rAd[4], *rBb[4], *rSc[3], *rOf[3];
  int p = 2;
  for (int i=0;i<4;i++){
    W[i]=(const float*)d_in[p++]; As[i]=(const float*)d_in[p++];
    Ad[i]=(const float*)d_in[p++]; Bb[i]=(const float*)d_in[p++];
    if (i<3){ Sc[i]=(const float*)d_in[p++]; Of[i]=(const float*)d_in[p++]; }
  }
  for (int i=0;i<4;i++){
    rW[i]=(const float*)d_in[p++]; rAs[i]=(const float*)d_in[p++];
    rAd[i]=(const float*)d_in[p++]; rBb[i]=(const float*)d_in[p++];
    if (i<3){ rSc[i]=(const float*)d_in[p++]; rOf[i]=(const float*)d_in[p++]; }
  }

  char* w = (char*)d_ws;
  auto carve = [&](size_t bytes)->void* {
    void* r = (void*)w;
    w += (bytes + 255) & ~(size_t)255;
    return r;
  };
  ushort* xb   = (ushort*)carve((size_t)BN_*736*2);
  ushort* hbuf = (ushort*)carve((size_t)BN_*HLD_*2);
  ushort* gbuf = (ushort*)carve((size_t)BN_*HLD_*2);
  ushort* sabf = (ushort*)carve((size_t)BN_*64*2);
  float* esed  = (float*)carve((size_t)BN_*24*4);
  float* stp   = (float*)carve((size_t)16*B_*HLD_*4);
  float* rsp   = (float*)carve((size_t)8*B_*FSS_*4);
  int* src_i   = (int*)carve((size_t)BE_*4);
  int* dst_i   = (int*)carve((size_t)BE_*4);
  int* cnt     = (int*)carve((size_t)2*BN_*4);   // cnt | fill contiguous
  int* fill    = cnt + BN_;
  int* rowptr  = (int*)carve((size_t)(BN_+1)*4);
  int* csr_src = (int*)carve((size_t)BE_*4);
  ushort* Wt[4];
  Wt[0] = (ushort*)carve((size_t)768*64*2);
  Wt[1] = (ushort*)carve((size_t)768*736*2);
  Wt[2] = (ushort*)carve((size_t)768*672*2);
  Wt[3] = (ushort*)carve((size_t)768*672*2);

  float* out = (float*)d_out;

  hipMemsetAsync(cnt, 0, (size_t)2*BN_*4, stream);

  k_indices<<<(BE_+255)/256, 256, 0, stream>>>(ns, src_i, dst_i, cnt);
  k_scan<<<1, 1024, 0, stream>>>(cnt, rowptr);
  k_scatter<<<(BE_+255)/256, 256, 0, stream>>>(src_i, dst_i, rowptr, fill, csr_src);
  k_sa<<<(BN_*64+255)/256, 256, 0, stream>>>(ns, a, sabf);

  WtP wtp;
  for (int i=0;i<4;i++){ wtp.Wr[i]=rW[i]; wtp.Wn[i]=W[i]; wtp.T[i]=Wt[i]; }
  k_wt_tr<<<1608, 256, 0, stream>>>(wtp);

  dim3 ggrid(6, BN_/64);   // 64-row tiles -> 768 blocks

  // L1: K=64 (shared sa), dn=128
  k_gemm<<<ggrid, 256, 0, stream>>>(sabf, Wt[0], hbuf, esed, rAs[0],rAd[0],As[0],Ad[0], 64, 128);
  k_agg<<<BN_/4, 256, 0, stream>>>(hbuf, esed, rowptr, csr_src, rBb[0], Bb[0], gbuf, 128);
  k_ln_stats<<<dim3(12, B_, 8), 256, 0, stream>>>(gbuf, stp);
  k_ln_apply<<<dim3(3, BN_/16), 256, 0, stream>>>(gbuf, stp, rSc[0],rOf[0],Sc[0],Of[0], xb, 128, 736);

  // L2: K=736, dn=64
  k_gemm<<<ggrid, 256, 0, stream>>>(xb, Wt[1], hbuf, esed, rAs[1],rAd[1],As[1],Ad[1], 736, 64);
  k_agg<<<BN_/4, 256, 0, stream>>>(hbuf, esed, rowptr, csr_src, rBb[1], Bb[1], gbuf, 64);
  k_ln_stats<<<dim3(12, B_, 8), 256, 0, stream>>>(gbuf, stp);
  k_ln_apply<<<dim3(3, BN_/16), 256, 0, stream>>>(gbuf, stp, rSc[1],rOf[1],Sc[1],Of[1], xb, 64, 672);

  // L3: K=672, dn=64
  k_gemm<<<ggrid, 256, 0, stream>>>(xb, Wt[2], hbuf, esed, rAs[2],rAd[2],As[2],Ad[2], 672, 64);
  k_agg<<<BN_/4, 256, 0, stream>>>(hbuf, esed, rowptr, csr_src, rBb[2], Bb[2], gbuf, 64);
  k_ln_stats<<<dim3(12, B_, 8), 256, 0, stream>>>(gbuf, stp);
  k_ln_apply<<<dim3(3, BN_/16), 256, 0, stream>>>(gbuf, stp, rSc[2],rOf[2],Sc[2],Of[2], xb, 64, 672);

  // L4: K=672, dn=32, no LN
  k_gemm<<<ggrid, 256, 0, stream>>>(xb, Wt[3], hbuf, esed, rAs[3],rAd[3],As[3],Ad[3], 672, 32);
  k_agg<<<BN_/4, 256, 0, stream>>>(hbuf, esed, rowptr, csr_src, rBb[3], Bb[3], gbuf, 32);

  k_rsum<<<dim3(10, B_, 8), 256, 0, stream>>>(gbuf, rsp);
  k_final<<<(OUT_R_ + B_*NSROW_ + 255)/256, 256, 0, stream>>>(rsp, gbuf, ns, out);
}